// Round 1
// 4046.354 us; speedup vs baseline: 5.2596x; 5.2596x over previous
//
#include <hip/hip_runtime.h>

typedef __bf16 bf16_t;
typedef __attribute__((ext_vector_type(8))) __bf16 bf16x8;
typedef __attribute__((ext_vector_type(4))) float f32x4;

__device__ __forceinline__ float gelu_exact(float x) {
    return 0.5f * x * (1.0f + erff(x * 0.70710678118654752f));
}

// ---------- tiled pure-VALU GEMM (validated structure) ----------
// C[m][n] = sum_k A[m][k] * B[n][k], bf16 storage, fp32 compute.
// EPI: 0 = plain bf16 out
//      1 = +bias, bf16 out
//      2 = gelu(acc+bias), bf16 out          (fc1)
//      3 = fp32 out = resid + acc + bias     (proj, fc2)
template<int EPI>
__global__ __launch_bounds__(256)
void vgemm(const bf16_t* __restrict__ A, int lda, long aBatch,
           const bf16_t* __restrict__ B, int ldb, long bBatch,
           bf16_t* __restrict__ C, int ldc, long cBatch,
           const float* __restrict__ bias, int K,
           float* __restrict__ Cf, const float* __restrict__ resid)
{
    __shared__ float As[32][72];
    __shared__ float Bs[32][72];
    const int t = threadIdx.x;
    const int tr = t >> 4, tc = t & 15;
    const int n0 = blockIdx.x * 64;
    const int m0 = blockIdx.y * 64;
    const int h  = blockIdx.z;
    A += (long)h * aBatch;
    B += (long)h * bBatch;
    C += (long)h * cBatch;

    float acc[4][4] = {};
    for (int k0 = 0; k0 < K; k0 += 32) {
        {
            int r = t >> 2, c = (t & 3) * 8;
            bf16x8 av = *(const bf16x8*)(A + (long)(m0 + r) * lda + (k0 + c));
            bf16x8 bv = *(const bf16x8*)(B + (long)(n0 + r) * ldb + (k0 + c));
            #pragma unroll
            for (int j = 0; j < 8; j++) {
                As[c + j][r] = (float)av[j];
                Bs[c + j][r] = (float)bv[j];
            }
        }
        __syncthreads();
        #pragma unroll 8
        for (int kk = 0; kk < 32; kk++) {
            float a[4], b[4];
            *(f32x4*)a = *(const f32x4*)&As[kk][tr * 4];
            *(f32x4*)b = *(const f32x4*)&Bs[kk][tc * 4];
            #pragma unroll
            for (int i = 0; i < 4; i++)
                #pragma unroll
                for (int j = 0; j < 4; j++)
                    acc[i][j] += a[i] * b[j];
        }
        __syncthreads();
    }
    #pragma unroll
    for (int i = 0; i < 4; i++) {
        int row = m0 + tr * 4 + i;
        #pragma unroll
        for (int j = 0; j < 4; j++) {
            int col = n0 + tc * 4 + j;
            float v = acc[i][j];
            if constexpr (EPI == 0) {
                C[(long)row * ldc + col] = (bf16_t)v;
            } else if constexpr (EPI == 1) {
                C[(long)row * ldc + col] = (bf16_t)(v + bias[col]);
            } else if constexpr (EPI == 2) {
                C[(long)row * ldc + col] = (bf16_t)gelu_exact(v + bias[col]);
            } else {
                long idx = (long)row * ldc + col;
                Cf[idx] = resid[idx] + v + bias[col];
            }
        }
    }
}

// Vt[h][e][m] = V[h][m][e],  V[h][m][e] = Y[m*27648 + 18432 + h*1536 + e]
__global__ __launch_bounds__(256)
void transpose_v(const bf16_t* __restrict__ Y, bf16_t* __restrict__ Vt)
{
    __shared__ bf16_t tile[64][65];
    int h  = blockIdx.z;
    int e0 = blockIdx.x * 64;
    int m0 = blockIdx.y * 64;
    int tx = threadIdx.x & 63, ty = threadIdx.x >> 6;
    #pragma unroll
    for (int i = 0; i < 64; i += 4)
        tile[ty + i][tx] = Y[(long)(m0 + ty + i) * 27648 + 18432 + h * 1536 + (e0 + tx)];
    __syncthreads();
    #pragma unroll
    for (int i = 0; i < 64; i += 4)
        Vt[((long)h * 1536 + e0 + ty + i) * 2304 + (m0 + tx)] = tile[tx][ty + i];
}

// LayerNorm, one block (256 thr) per row of 192. LDS tree reduction. fp32 in -> bf16 out.
__global__ __launch_bounds__(256)
void ln_dumb(const float* __restrict__ x, const float* __restrict__ g,
             const float* __restrict__ b, bf16_t* __restrict__ o)
{
    __shared__ float red[256];
    long row = blockIdx.x;
    int t = threadIdx.x;
    float v = (t < 192) ? x[row * 192 + t] : 0.f;
    red[t] = v;
    __syncthreads();
    for (int s = 128; s > 0; s >>= 1) { if (t < s) red[t] += red[t + s]; __syncthreads(); }
    float mean = red[0] * (1.f / 192.f);
    __syncthreads();
    float d = (t < 192) ? (v - mean) : 0.f;
    red[t] = d * d;
    __syncthreads();
    for (int s = 128; s > 0; s >>= 1) { if (t < s) red[t] += red[t + s]; __syncthreads(); }
    float rs = rsqrtf(red[0] * (1.f / 192.f) + 1e-5f);
    if (t < 192) o[row * 192 + t] = (bf16_t)(d * rs * g[t] + b[t]);
}

// softmax over 2304 bf16 logits (scale folded), in place. LDS tree, no shuffles.
__global__ __launch_bounds__(256)
void softmax_dumb(bf16_t* __restrict__ S)
{
    const float SC = 0.17677669529663687f;  // 32^-0.5
    __shared__ float red[256];
    long base = (long)blockIdx.x * 2304;
    int t = threadIdx.x;
    float v[9];
    float mx = -1e30f;
    #pragma unroll
    for (int i = 0; i < 9; ++i) {
        v[i] = (float)S[base + t + i * 256] * SC;
        mx = fmaxf(mx, v[i]);
    }
    red[t] = mx;
    __syncthreads();
    for (int s = 128; s > 0; s >>= 1) { if (t < s) red[t] = fmaxf(red[t], red[t + s]); __syncthreads(); }
    mx = red[0];
    __syncthreads();
    float sum = 0.f;
    #pragma unroll
    for (int i = 0; i < 9; ++i) { v[i] = __expf(v[i] - mx); sum += v[i]; }
    red[t] = sum;
    __syncthreads();
    for (int s = 128; s > 0; s >>= 1) { if (t < s) red[t] += red[t + s]; __syncthreads(); }
    float inv = 1.f / red[0];
    #pragma unroll
    for (int i = 0; i < 9; ++i) S[base + t + i * 256] = (bf16_t)(v[i] * inv);
}

__global__ __launch_bounds__(256)
void cast_wq(const float* __restrict__ w, int n, bf16_t* __restrict__ o)
{
    int i = blockIdx.x * 256 + threadIdx.x;
    if (i < n) o[i] = (bf16_t)w[i];
}

extern "C" void kernel_launch(void* const* d_in, const int* in_sizes, int n_in,
                              void* d_out, int out_size, void* d_ws, size_t ws_size,
                              hipStream_t stream)
{
    (void)in_sizes; (void)n_in; (void)out_size; (void)ws_size;
    const float* x      = (const float*)d_in[0];
    const float* n1g    = (const float*)d_in[1];
    const float* n1b    = (const float*)d_in[2];
    const float* qkv_w  = (const float*)d_in[3];
    const float* qkv_b  = (const float*)d_in[4];
    const float* proj_w = (const float*)d_in[5];
    const float* proj_b = (const float*)d_in[6];
    const float* n2g    = (const float*)d_in[7];
    const float* n2b    = (const float*)d_in[8];
    const float* fc1_w  = (const float*)d_in[9];
    const float* fc1_b  = (const float*)d_in[10];
    const float* fc2_w  = (const float*)d_in[11];
    const float* fc2_b  = (const float*)d_in[12];
    float* out = (float*)d_out;

    char* ws = (char*)d_ws;
    size_t off = 0;
    auto alloc = [&](size_t nbytes) -> void* {
        off = (off + 255) & ~(size_t)255;
        void* p = ws + off;
        off += nbytes;
        return p;
    };

    bf16_t* Wq   = (bf16_t*)alloc((size_t)576 * 192 * 2);
    bf16_t* Wp   = (bf16_t*)alloc((size_t)192 * 192 * 2);
    bf16_t* W1   = (bf16_t*)alloc((size_t)768 * 192 * 2);
    bf16_t* W2   = (bf16_t*)alloc((size_t)192 * 768 * 2);
    bf16_t* Hbuf = (bf16_t*)alloc((size_t)110592 * 192 * 2);   // ln1 out -> O -> ln2 out
    bf16_t* Qkv  = (bf16_t*)alloc((size_t)110592 * 768 * 2);   // qkv(576)+Vt tail -> fc1(768)
    bf16_t* Vt   = Qkv + (size_t)110592 * 576;
    bf16_t* Sbuf = (bf16_t*)d_out;                              // 63.7 MB <= 85 MB, dead until proj

    cast_wq<<<432, 256, 0, stream>>>(qkv_w, 576 * 192, Wq);
    cast_wq<<<144, 256, 0, stream>>>(proj_w, 192 * 192, Wp);
    cast_wq<<<576, 256, 0, stream>>>(fc1_w, 768 * 192, W1);
    cast_wq<<<576, 256, 0, stream>>>(fc2_w, 192 * 768, W2);

    // LN1: x -> Hbuf (bf16)
    ln_dumb<<<110592, 256, 0, stream>>>(x, n1g, n1b, Hbuf);
    // QKV: (110592x192)@(576x192)^T + b -> Qkv
    vgemm<1><<<dim3(9, 1728, 1), 256, 0, stream>>>(
        Hbuf, 192, 0, Wq, 192, 0, Qkv, 576, 0, qkv_b, 192, nullptr, nullptr);
    // Vt[h][e][m] = V[h][m][e]
    transpose_v<<<dim3(24, 36, 6), 256, 0, stream>>>(Qkv, Vt);
    // S = Q @ K^T per head (z=6): 2304x2304, K=1536
    vgemm<0><<<dim3(36, 36, 6), 256, 0, stream>>>(
        Qkv, 27648, 1536, Qkv + 9216, 27648, 1536,
        Sbuf, 2304, (long)2304 * 2304, nullptr, 1536, nullptr, nullptr);
    // softmax rows (scale inside), in place
    softmax_dumb<<<13824, 256, 0, stream>>>(Sbuf);
    // O = P @ Vt^T per head: 2304x1536, K=2304
    vgemm<0><<<dim3(24, 36, 6), 256, 0, stream>>>(
        Sbuf, 2304, (long)2304 * 2304, Vt, 2304, (long)1536 * 2304,
        Hbuf, 9216, 1536, nullptr, 2304, nullptr, nullptr);
    // x1 = x + O @ Wp^T + pb -> out (fp32), tiled GEMM epilogue
    vgemm<3><<<dim3(3, 1728, 1), 256, 0, stream>>>(
        Hbuf, 192, 0, Wp, 192, 0, nullptr, 192, 0, proj_b, 192, out, x);
    // LN2: x1 -> Hbuf (bf16)
    ln_dumb<<<110592, 256, 0, stream>>>(out, n2g, n2b, Hbuf);
    // fc1 + gelu -> Qkv (768 cols), tiled GEMM epilogue
    vgemm<2><<<dim3(12, 1728, 1), 256, 0, stream>>>(
        Hbuf, 192, 0, W1, 192, 0, Qkv, 768, 0, fc1_b, 192, nullptr, nullptr);
    // fc2 + resid -> out (fp32, in-place resid), tiled GEMM epilogue
    vgemm<3><<<dim3(3, 1728, 1), 256, 0, stream>>>(
        Qkv, 768, 0, W2, 768, 0, nullptr, 192, 0, fc2_b, 768, out, out);
}

// Round 2
// 1016.192 us; speedup vs baseline: 20.9431x; 3.9819x over previous
//
#include <hip/hip_runtime.h>

typedef __bf16 bf16_t;
typedef __attribute__((ext_vector_type(8))) __bf16 bf16x8;
typedef __attribute__((ext_vector_type(4))) float f32x4;

__device__ __forceinline__ float gelu_exact(float x) {
    return 0.5f * x * (1.0f + erff(x * 0.70710678118654752f));
}

// ---------- MFMA bf16 GEMM, m97 structure ----------
// C[m][n] = sum_k A[m][k] * B[n][k]  (both operands K-major, bf16)
// 256 threads = 4 waves in 2x2 grid; each wave owns (BM/2)x(BN/2);
// 16x16x32 bf16 MFMA; global_load_lds width-16 staging into linear LDS.
// EPI: 0 = plain bf16 out
//      1 = +bias, bf16 out                   (qkv)
//      2 = gelu(acc+bias), bf16 out          (fc1)
//      3 = fp32 out = resid + acc + bias     (proj, fc2)
template<int BM, int BN, int EPI>
__global__ __launch_bounds__(256)
void mgemm(const bf16_t* __restrict__ A, int lda, long aBatch,
           const bf16_t* __restrict__ B, int ldb, long bBatch,
           bf16_t* __restrict__ C, int ldc, long cBatch,
           const float* __restrict__ bias, int K,
           float* __restrict__ Cf, const float* __restrict__ resid)
{
    constexpr int MR = BM / 32;   // 16x16 frags per wave, M dir
    constexpr int NR = BN / 32;   // 16x16 frags per wave, N dir
    __shared__ __align__(16) bf16_t As[BM * 32];
    __shared__ __align__(16) bf16_t Bs[BN * 32];
    const int t    = threadIdx.x;
    const int w    = t >> 6;
    const int lane = t & 63;
    const int wr   = w >> 1, wc = w & 1;
    const long n0 = (long)blockIdx.x * BN;
    const long m0 = (long)blockIdx.y * BM;
    const int  h  = blockIdx.z;
    A += (long)h * aBatch;
    B += (long)h * bBatch;
    if constexpr (EPI != 3) C += (long)h * cBatch;

    f32x4 acc[MR][NR] = {};

    const int sr = t >> 2;          // 0..63: row within a 64-row staging chunk
    const int sc = (t & 3) * 8;     // k-offset (8 bf16 = 16B)
    const int kq   = (lane >> 4) * 8;   // fragment k-offset: 0,8,16,24
    const int lrow = lane & 15;         // fragment row/col within 16

    for (int k0 = 0; k0 < K; k0 += 32) {
        // ---- stage A tile [BM][32] (linear LDS; dest = wave-uniform base + lane*16) ----
        #pragma unroll
        for (int c = 0; c < BM / 64; ++c) {
            const bf16_t* src = A + (m0 + c * 64 + sr) * (long)lda + (k0 + sc);
            __builtin_amdgcn_global_load_lds(
                (__attribute__((address_space(1))) void*)(bf16_t*)src,
                (__attribute__((address_space(3))) void*)(As + c * 2048 + w * 512),
                16, 0, 0);
        }
        // ---- stage B tile [BN][32] ----
        #pragma unroll
        for (int c = 0; c < BN / 64; ++c) {
            const bf16_t* src = B + (n0 + c * 64 + sr) * (long)ldb + (k0 + sc);
            __builtin_amdgcn_global_load_lds(
                (__attribute__((address_space(1))) void*)(bf16_t*)src,
                (__attribute__((address_space(3))) void*)(Bs + c * 2048 + w * 512),
                16, 0, 0);
        }
        __syncthreads();   // compiler drains vmcnt before s_barrier (m97-verified)

        // ---- fragments: A lane l holds row (l&15), k=(l>>4)*8..+7; B mirrors with col ----
        bf16x8 af[MR], bfr[NR];
        #pragma unroll
        for (int i = 0; i < MR; ++i)
            af[i] = *(const bf16x8*)(As + (wr * (BM / 2) + i * 16 + lrow) * 32 + kq);
        #pragma unroll
        for (int j = 0; j < NR; ++j)
            bfr[j] = *(const bf16x8*)(Bs + (wc * (BN / 2) + j * 16 + lrow) * 32 + kq);
        #pragma unroll
        for (int i = 0; i < MR; ++i)
            #pragma unroll
            for (int j = 0; j < NR; ++j)
                acc[i][j] = __builtin_amdgcn_mfma_f32_16x16x32_bf16(af[i], bfr[j], acc[i][j], 0, 0, 0);
        __syncthreads();
    }

    // ---- epilogue: D mapping col=lane&15, row=(lane>>4)*4+reg (m89/m91-verified) ----
    const int ccol  = lane & 15;
    const int crow4 = (lane >> 4) * 4;
    #pragma unroll
    for (int i = 0; i < MR; ++i) {
        long rowb = m0 + wr * (BM / 2) + i * 16 + crow4;
        #pragma unroll
        for (int j = 0; j < NR; ++j) {
            long col = n0 + wc * (BN / 2) + j * 16 + ccol;
            #pragma unroll
            for (int r = 0; r < 4; ++r) {
                float v = acc[i][j][r];
                long row = rowb + r;
                if constexpr (EPI == 0) {
                    C[row * ldc + col] = (bf16_t)v;
                } else if constexpr (EPI == 1) {
                    C[row * ldc + col] = (bf16_t)(v + bias[col]);
                } else if constexpr (EPI == 2) {
                    C[row * ldc + col] = (bf16_t)gelu_exact(v + bias[col]);
                } else {
                    long idx = row * ldc + col;
                    Cf[idx] = resid[idx] + v + bias[col];
                }
            }
        }
    }
}

// Vt[h][e][m] = V[h][m][e],  V[h][m][e] = Y[m*27648 + 18432 + h*1536 + e]
__global__ __launch_bounds__(256)
void transpose_v(const bf16_t* __restrict__ Y, bf16_t* __restrict__ Vt)
{
    __shared__ bf16_t tile[64][65];
    int h  = blockIdx.z;
    int e0 = blockIdx.x * 64;
    int m0 = blockIdx.y * 64;
    int tx = threadIdx.x & 63, ty = threadIdx.x >> 6;
    #pragma unroll
    for (int i = 0; i < 64; i += 4)
        tile[ty + i][tx] = Y[(long)(m0 + ty + i) * 27648 + 18432 + h * 1536 + (e0 + tx)];
    __syncthreads();
    #pragma unroll
    for (int i = 0; i < 64; i += 4)
        Vt[((long)h * 1536 + e0 + ty + i) * 2304 + (m0 + tx)] = tile[tx][ty + i];
}

// LayerNorm, one block (256 thr) per row of 192. LDS tree reduction. fp32 in -> bf16 out.
__global__ __launch_bounds__(256)
void ln_dumb(const float* __restrict__ x, const float* __restrict__ g,
             const float* __restrict__ b, bf16_t* __restrict__ o)
{
    __shared__ float red[256];
    long row = blockIdx.x;
    int t = threadIdx.x;
    float v = (t < 192) ? x[row * 192 + t] : 0.f;
    red[t] = v;
    __syncthreads();
    for (int s = 128; s > 0; s >>= 1) { if (t < s) red[t] += red[t + s]; __syncthreads(); }
    float mean = red[0] * (1.f / 192.f);
    __syncthreads();
    float d = (t < 192) ? (v - mean) : 0.f;
    red[t] = d * d;
    __syncthreads();
    for (int s = 128; s > 0; s >>= 1) { if (t < s) red[t] += red[t + s]; __syncthreads(); }
    float rs = rsqrtf(red[0] * (1.f / 192.f) + 1e-5f);
    if (t < 192) o[row * 192 + t] = (bf16_t)(d * rs * g[t] + b[t]);
}

// softmax over 2304 bf16 logits (scale folded), in place. LDS tree, no shuffles.
__global__ __launch_bounds__(256)
void softmax_dumb(bf16_t* __restrict__ S)
{
    const float SC = 0.17677669529663687f;  // 32^-0.5
    __shared__ float red[256];
    long base = (long)blockIdx.x * 2304;
    int t = threadIdx.x;
    float v[9];
    float mx = -1e30f;
    #pragma unroll
    for (int i = 0; i < 9; ++i) {
        v[i] = (float)S[base + t + i * 256] * SC;
        mx = fmaxf(mx, v[i]);
    }
    red[t] = mx;
    __syncthreads();
    for (int s = 128; s > 0; s >>= 1) { if (t < s) red[t] = fmaxf(red[t], red[t + s]); __syncthreads(); }
    mx = red[0];
    __syncthreads();
    float sum = 0.f;
    #pragma unroll
    for (int i = 0; i < 9; ++i) { v[i] = __expf(v[i] - mx); sum += v[i]; }
    red[t] = sum;
    __syncthreads();
    for (int s = 128; s > 0; s >>= 1) { if (t < s) red[t] += red[t + s]; __syncthreads(); }
    float inv = 1.f / red[0];
    #pragma unroll
    for (int i = 0; i < 9; ++i) S[base + t + i * 256] = (bf16_t)(v[i] * inv);
}

__global__ __launch_bounds__(256)
void cast_wq(const float* __restrict__ w, int n, bf16_t* __restrict__ o)
{
    int i = blockIdx.x * 256 + threadIdx.x;
    if (i < n) o[i] = (bf16_t)w[i];
}

extern "C" void kernel_launch(void* const* d_in, const int* in_sizes, int n_in,
                              void* d_out, int out_size, void* d_ws, size_t ws_size,
                              hipStream_t stream)
{
    (void)in_sizes; (void)n_in; (void)out_size; (void)ws_size;
    const float* x      = (const float*)d_in[0];
    const float* n1g    = (const float*)d_in[1];
    const float* n1b    = (const float*)d_in[2];
    const float* qkv_w  = (const float*)d_in[3];
    const float* qkv_b  = (const float*)d_in[4];
    const float* proj_w = (const float*)d_in[5];
    const float* proj_b = (const float*)d_in[6];
    const float* n2g    = (const float*)d_in[7];
    const float* n2b    = (const float*)d_in[8];
    const float* fc1_w  = (const float*)d_in[9];
    const float* fc1_b  = (const float*)d_in[10];
    const float* fc2_w  = (const float*)d_in[11];
    const float* fc2_b  = (const float*)d_in[12];
    float* out = (float*)d_out;

    char* ws = (char*)d_ws;
    size_t off = 0;
    auto alloc = [&](size_t nbytes) -> void* {
        off = (off + 255) & ~(size_t)255;
        void* p = ws + off;
        off += nbytes;
        return p;
    };

    bf16_t* Wq   = (bf16_t*)alloc((size_t)576 * 192 * 2);
    bf16_t* Wp   = (bf16_t*)alloc((size_t)192 * 192 * 2);
    bf16_t* W1   = (bf16_t*)alloc((size_t)768 * 192 * 2);
    bf16_t* W2   = (bf16_t*)alloc((size_t)192 * 768 * 2);
    bf16_t* Hbuf = (bf16_t*)alloc((size_t)110592 * 192 * 2);   // ln1 out -> O -> ln2 out
    bf16_t* Qkv  = (bf16_t*)alloc((size_t)110592 * 768 * 2);   // qkv(576)+Vt tail -> fc1(768)
    bf16_t* Vt   = Qkv + (size_t)110592 * 576;
    bf16_t* Sbuf = (bf16_t*)d_out;                              // 63.7 MB <= 85 MB, dead until proj

    cast_wq<<<432, 256, 0, stream>>>(qkv_w, 576 * 192, Wq);
    cast_wq<<<144, 256, 0, stream>>>(proj_w, 192 * 192, Wp);
    cast_wq<<<576, 256, 0, stream>>>(fc1_w, 768 * 192, W1);
    cast_wq<<<576, 256, 0, stream>>>(fc2_w, 192 * 768, W2);

    // LN1: x -> Hbuf (bf16)
    ln_dumb<<<110592, 256, 0, stream>>>(x, n1g, n1b, Hbuf);
    // QKV: (110592x192)@(576x192)^T + b -> Qkv
    mgemm<128, 64, 1><<<dim3(9, 864, 1), 256, 0, stream>>>(
        Hbuf, 192, 0, Wq, 192, 0, Qkv, 576, 0, qkv_b, 192, nullptr, nullptr);
    // Vt[h][e][m] = V[h][m][e]
    transpose_v<<<dim3(24, 36, 6), 256, 0, stream>>>(Qkv, Vt);
    // S = Q @ K^T per head (z=6): 2304x2304, K=1536
    mgemm<128, 128, 0><<<dim3(18, 18, 6), 256, 0, stream>>>(
        Qkv, 27648, 1536, Qkv + 9216, 27648, 1536,
        Sbuf, 2304, (long)2304 * 2304, nullptr, 1536, nullptr, nullptr);
    // softmax rows (scale inside), in place
    softmax_dumb<<<13824, 256, 0, stream>>>(Sbuf);
    // O = P @ Vt^T per head: 2304x1536, K=2304
    mgemm<128, 128, 0><<<dim3(12, 18, 6), 256, 0, stream>>>(
        Sbuf, 2304, (long)2304 * 2304, Vt, 2304, (long)1536 * 2304,
        Hbuf, 9216, 1536, nullptr, 2304, nullptr, nullptr);
    // x1 = x + O @ Wp^T + pb -> out (fp32)
    mgemm<128, 64, 3><<<dim3(3, 864, 1), 256, 0, stream>>>(
        Hbuf, 192, 0, Wp, 192, 0, nullptr, 192, 0, proj_b, 192, out, x);
    // LN2: x1 -> Hbuf (bf16)
    ln_dumb<<<110592, 256, 0, stream>>>(out, n2g, n2b, Hbuf);
    // fc1 + gelu -> Qkv (768 cols)
    mgemm<128, 128, 2><<<dim3(6, 864, 1), 256, 0, stream>>>(
        Hbuf, 192, 0, W1, 192, 0, Qkv, 768, 0, fc1_b, 192, nullptr, nullptr);
    // fc2 + resid -> out (fp32, in-place resid)
    mgemm<128, 64, 3><<<dim3(3, 864, 1), 256, 0, stream>>>(
        Qkv, 768, 0, W2, 768, 0, nullptr, 192, 0, fc2_b, 768, out, out);
}

// Round 3
// 830.222 us; speedup vs baseline: 25.6343x; 1.2240x over previous
//
#include <hip/hip_runtime.h>

typedef __bf16 bf16_t;
typedef __attribute__((ext_vector_type(8))) __bf16 bf16x8;
typedef __attribute__((ext_vector_type(4))) float f32x4;

__device__ __forceinline__ float gelu_exact(float x) {
    return 0.5f * x * (1.0f + erff(x * 0.70710678118654752f));
}

// ---------- MFMA bf16 GEMM, m97 structure ----------
// C[m][n] = sum_k A[m][k] * B[n][k]  (both operands K-major, bf16)
// 256 threads = 4 waves in 2x2 grid; each wave owns (BM/2)x(BN/2);
// 16x16x32 bf16 MFMA; global_load_lds width-16 staging into linear LDS.
// EPI: 0 = plain bf16 out
//      1 = +bias, bf16 out                   (qkv)
//      2 = gelu(acc+bias), bf16 out          (fc1)
//      3 = fp32 out = resid + acc + bias     (proj, fc2)
// SWZ: 1 = XCD-chunked block remap (grid size must be divisible by 8)
template<int BM, int BN, int EPI, int SWZ>
__global__ __launch_bounds__(256)
void mgemm(const bf16_t* __restrict__ A, int lda, long aBatch,
           const bf16_t* __restrict__ B, int ldb, long bBatch,
           bf16_t* __restrict__ C, int ldc, long cBatch,
           const float* __restrict__ bias, int K,
           float* __restrict__ Cf, const float* __restrict__ resid)
{
    constexpr int MR = BM / 32;   // 16x16 frags per wave, M dir
    constexpr int NR = BN / 32;   // 16x16 frags per wave, N dir
    __shared__ __align__(16) bf16_t As[BM * 32];
    __shared__ __align__(16) bf16_t Bs[BN * 32];
    const int t    = threadIdx.x;
    const int w    = t >> 6;
    const int lane = t & 63;
    const int wr   = w >> 1, wc = w & 1;

    unsigned bx = blockIdx.x, by = blockIdx.y, bz = blockIdx.z;
    if constexpr (SWZ) {
        const unsigned gx = gridDim.x, gy = gridDim.y, gz = gridDim.z;
        unsigned lin = (bz * gy + by) * gx + bx;
        const unsigned cpx = (gx * gy * gz) >> 3;   // grid % 8 == 0 at all call sites
        lin = (lin & 7) * cpx + (lin >> 3);
        bx = lin % gx; lin /= gx;
        by = lin % gy; bz = lin / gy;
    }

    const long n0 = (long)bx * BN;
    const long m0 = (long)by * BM;
    A += (long)bz * aBatch;
    B += (long)bz * bBatch;
    if constexpr (EPI != 3) C += (long)bz * cBatch;

    f32x4 acc[MR][NR] = {};

    const int sr = t >> 2;          // 0..63: row within a 64-row staging chunk
    const int sc = (t & 3) * 8;     // k-offset (8 bf16 = 16B)
    const int kq   = (lane >> 4) * 8;   // fragment k-offset: 0,8,16,24
    const int lrow = lane & 15;         // fragment row/col within 16

    for (int k0 = 0; k0 < K; k0 += 32) {
        #pragma unroll
        for (int c = 0; c < BM / 64; ++c) {
            const bf16_t* src = A + (m0 + c * 64 + sr) * (long)lda + (k0 + sc);
            __builtin_amdgcn_global_load_lds(
                (__attribute__((address_space(1))) void*)(bf16_t*)src,
                (__attribute__((address_space(3))) void*)(As + c * 2048 + w * 512),
                16, 0, 0);
        }
        #pragma unroll
        for (int c = 0; c < BN / 64; ++c) {
            const bf16_t* src = B + (n0 + c * 64 + sr) * (long)ldb + (k0 + sc);
            __builtin_amdgcn_global_load_lds(
                (__attribute__((address_space(1))) void*)(bf16_t*)src,
                (__attribute__((address_space(3))) void*)(Bs + c * 2048 + w * 512),
                16, 0, 0);
        }
        __syncthreads();

        bf16x8 af[MR], bfr[NR];
        #pragma unroll
        for (int i = 0; i < MR; ++i)
            af[i] = *(const bf16x8*)(As + (wr * (BM / 2) + i * 16 + lrow) * 32 + kq);
        #pragma unroll
        for (int j = 0; j < NR; ++j)
            bfr[j] = *(const bf16x8*)(Bs + (wc * (BN / 2) + j * 16 + lrow) * 32 + kq);
        #pragma unroll
        for (int i = 0; i < MR; ++i)
            #pragma unroll
            for (int j = 0; j < NR; ++j)
                acc[i][j] = __builtin_amdgcn_mfma_f32_16x16x32_bf16(af[i], bfr[j], acc[i][j], 0, 0, 0);
        __syncthreads();
    }

    // D mapping col=lane&15, row=(lane>>4)*4+reg (m89/m91-verified)
    const int ccol  = lane & 15;
    const int crow4 = (lane >> 4) * 4;
    #pragma unroll
    for (int i = 0; i < MR; ++i) {
        long rowb = m0 + wr * (BM / 2) + i * 16 + crow4;
        #pragma unroll
        for (int j = 0; j < NR; ++j) {
            long col = n0 + wc * (BN / 2) + j * 16 + ccol;
            #pragma unroll
            for (int r = 0; r < 4; ++r) {
                float v = acc[i][j][r];
                long row = rowb + r;
                if constexpr (EPI == 0) {
                    C[row * ldc + col] = (bf16_t)v;
                } else if constexpr (EPI == 1) {
                    C[row * ldc + col] = (bf16_t)(v + bias[col]);
                } else if constexpr (EPI == 2) {
                    C[row * ldc + col] = (bf16_t)gelu_exact(v + bias[col]);
                } else {
                    long idx = row * ldc + col;
                    Cf[idx] = resid[idx] + v + bias[col];
                }
            }
        }
    }
}

// Vt[h][e][m] = V[h][m][e],  V[h][m][e] = Y[m*27648 + 18432 + h*1536 + e]
// bf16x8 loads/stores through XOR-swizzled LDS tile (chunk ^= row>>3, stride 80).
__global__ __launch_bounds__(256)
void transpose_v(const bf16_t* __restrict__ Y, bf16_t* __restrict__ Vt)
{
    __shared__ bf16_t tile[64][80];
    const int h  = blockIdx.z;
    const int e0 = blockIdx.x * 64;
    const int m0 = blockIdx.y * 64;
    const int t  = threadIdx.x;
    const int lr = t >> 3;          // 0..31
    const int lc8 = t & 7;          // chunk index 0..7

    #pragma unroll
    for (int i = 0; i < 64; i += 32) {
        int row = lr + i;           // m-local
        bf16x8 vv = *(const bf16x8*)(Y + (long)(m0 + row) * 27648 + 18432 + h * 1536 + e0 + lc8 * 8);
        int cs = lc8 ^ (row >> 3);  // swizzled e-chunk
        *(bf16x8*)&tile[row][cs * 8] = vv;
    }
    __syncthreads();
    #pragma unroll
    for (int i = 0; i < 64; i += 32) {
        int er = lr + i;            // e-local
        bf16x8 vv;
        #pragma unroll
        for (int j = 0; j < 8; ++j) {
            int row = lc8 * 8 + j;  // m-local
            int cs = (er >> 3) ^ lc8;   // (row>>3) == lc8
            vv[j] = tile[row][cs * 8 + (er & 7)];
        }
        *(bf16x8*)(Vt + ((long)h * 1536 + e0 + er) * 2304 + m0 + lc8 * 8) = vv;
    }
}

// LayerNorm: one WAVE per 192-row, shfl reductions, zero barriers. fp32 in -> bf16 out.
__global__ __launch_bounds__(256)
void ln_fast(const float* __restrict__ x, const float* __restrict__ g,
             const float* __restrict__ b, bf16_t* __restrict__ o, int nrows)
{
    const int lane = threadIdx.x & 63;
    const int wave = threadIdx.x >> 6;
    const float g0 = g[lane], g1 = g[lane + 64], g2 = g[lane + 128];
    const float b0 = b[lane], b1 = b[lane + 64], b2 = b[lane + 128];
    for (long row = (long)blockIdx.x * 4 + wave; row < nrows; row += (long)gridDim.x * 4) {
        const float* xr = x + row * 192;
        float v0 = xr[lane], v1 = xr[lane + 64], v2 = xr[lane + 128];
        float s  = v0 + v1 + v2;
        float ss = v0 * v0 + v1 * v1 + v2 * v2;
        #pragma unroll
        for (int d = 32; d > 0; d >>= 1) {
            s  += __shfl_xor(s, d);
            ss += __shfl_xor(ss, d);
        }
        float mean = s * (1.f / 192.f);
        float var  = ss * (1.f / 192.f) - mean * mean;
        float rs   = rsqrtf(var + 1e-5f);
        bf16_t* orow = o + row * 192;
        orow[lane]       = (bf16_t)((v0 - mean) * rs * g0 + b0);
        orow[lane + 64]  = (bf16_t)((v1 - mean) * rs * g1 + b1);
        orow[lane + 128] = (bf16_t)((v2 - mean) * rs * g2 + b2);
    }
}

// softmax over 2304 bf16 logits (scale folded), in place. Wave shfl + 4-entry LDS, 2 barriers.
__global__ __launch_bounds__(256)
void softmax_fast(bf16_t* __restrict__ S)
{
    const float SC = 0.17677669529663687f;  // 32^-0.5
    __shared__ float wmax[4], wsum[4];
    const long base = (long)blockIdx.x * 2304;
    const int t = threadIdx.x;
    const int lane = t & 63, w = t >> 6;
    float v[9];
    float mx = -1e30f;
    #pragma unroll
    for (int i = 0; i < 9; ++i) {
        v[i] = (float)S[base + t + i * 256] * SC;
        mx = fmaxf(mx, v[i]);
    }
    #pragma unroll
    for (int d = 32; d > 0; d >>= 1) mx = fmaxf(mx, __shfl_xor(mx, d));
    if (lane == 0) wmax[w] = mx;
    __syncthreads();
    mx = fmaxf(fmaxf(wmax[0], wmax[1]), fmaxf(wmax[2], wmax[3]));
    float sum = 0.f;
    #pragma unroll
    for (int i = 0; i < 9; ++i) { v[i] = __expf(v[i] - mx); sum += v[i]; }
    #pragma unroll
    for (int d = 32; d > 0; d >>= 1) sum += __shfl_xor(sum, d);
    if (lane == 0) wsum[w] = sum;
    __syncthreads();
    const float inv = 1.f / (wsum[0] + wsum[1] + wsum[2] + wsum[3]);
    #pragma unroll
    for (int i = 0; i < 9; ++i) S[base + t + i * 256] = (bf16_t)(v[i] * inv);
}

__global__ __launch_bounds__(256)
void cast_wq(const float* __restrict__ w, int n, bf16_t* __restrict__ o)
{
    int i = blockIdx.x * 256 + threadIdx.x;
    if (i < n) o[i] = (bf16_t)w[i];
}

extern "C" void kernel_launch(void* const* d_in, const int* in_sizes, int n_in,
                              void* d_out, int out_size, void* d_ws, size_t ws_size,
                              hipStream_t stream)
{
    (void)in_sizes; (void)n_in; (void)out_size; (void)ws_size;
    const float* x      = (const float*)d_in[0];
    const float* n1g    = (const float*)d_in[1];
    const float* n1b    = (const float*)d_in[2];
    const float* qkv_w  = (const float*)d_in[3];
    const float* qkv_b  = (const float*)d_in[4];
    const float* proj_w = (const float*)d_in[5];
    const float* proj_b = (const float*)d_in[6];
    const float* n2g    = (const float*)d_in[7];
    const float* n2b    = (const float*)d_in[8];
    const float* fc1_w  = (const float*)d_in[9];
    const float* fc1_b  = (const float*)d_in[10];
    const float* fc2_w  = (const float*)d_in[11];
    const float* fc2_b  = (const float*)d_in[12];
    float* out = (float*)d_out;

    char* ws = (char*)d_ws;
    size_t off = 0;
    auto alloc = [&](size_t nbytes) -> void* {
        off = (off + 255) & ~(size_t)255;
        void* p = ws + off;
        off += nbytes;
        return p;
    };

    bf16_t* Wq   = (bf16_t*)alloc((size_t)576 * 192 * 2);
    bf16_t* Wp   = (bf16_t*)alloc((size_t)192 * 192 * 2);
    bf16_t* W1   = (bf16_t*)alloc((size_t)768 * 192 * 2);
    bf16_t* W2   = (bf16_t*)alloc((size_t)192 * 768 * 2);
    bf16_t* Hbuf = (bf16_t*)alloc((size_t)110592 * 192 * 2);   // ln1 out -> O -> ln2 out
    bf16_t* Qkv  = (bf16_t*)alloc((size_t)110592 * 768 * 2);   // qkv(576)+Vt tail -> fc1(768)
    bf16_t* Vt   = Qkv + (size_t)110592 * 576;
    bf16_t* Sbuf = (bf16_t*)d_out;                              // 63.7 MB <= 85 MB, dead until proj

    cast_wq<<<432, 256, 0, stream>>>(qkv_w, 576 * 192, Wq);
    cast_wq<<<144, 256, 0, stream>>>(proj_w, 192 * 192, Wp);
    cast_wq<<<576, 256, 0, stream>>>(fc1_w, 768 * 192, W1);
    cast_wq<<<576, 256, 0, stream>>>(fc2_w, 192 * 768, W2);

    // LN1: x -> Hbuf (bf16)
    ln_fast<<<2048, 256, 0, stream>>>(x, n1g, n1b, Hbuf, 110592);
    // QKV: (110592x192)@(576x192)^T + b -> Qkv
    mgemm<128, 64, 1, 0><<<dim3(9, 864, 1), 256, 0, stream>>>(
        Hbuf, 192, 0, Wq, 192, 0, Qkv, 576, 0, qkv_b, 192, nullptr, nullptr);
    // Vt[h][e][m] = V[h][m][e]
    transpose_v<<<dim3(24, 36, 6), 256, 0, stream>>>(Qkv, Vt);
    // S = Q @ K^T per head (z=6): 2304x2304, K=1536   [grid 1944 % 8 == 0]
    mgemm<128, 128, 0, 1><<<dim3(18, 18, 6), 256, 0, stream>>>(
        Qkv, 27648, 1536, Qkv + 9216, 27648, 1536,
        Sbuf, 2304, (long)2304 * 2304, nullptr, 1536, nullptr, nullptr);
    // softmax rows (scale inside), in place
    softmax_fast<<<13824, 256, 0, stream>>>(Sbuf);
    // O = P @ Vt^T per head: 2304x1536, K=2304        [grid 1296 % 8 == 0]
    mgemm<128, 128, 0, 1><<<dim3(12, 18, 6), 256, 0, stream>>>(
        Sbuf, 2304, (long)2304 * 2304, Vt, 2304, (long)1536 * 2304,
        Hbuf, 9216, 1536, nullptr, 2304, nullptr, nullptr);
    // x1 = x + O @ Wp^T + pb -> out (fp32)
    mgemm<128, 64, 3, 0><<<dim3(3, 864, 1), 256, 0, stream>>>(
        Hbuf, 192, 0, Wp, 192, 0, nullptr, 192, 0, proj_b, 192, out, x);
    // LN2: x1 -> Hbuf (bf16)
    ln_fast<<<2048, 256, 0, stream>>>(out, n2g, n2b, Hbuf, 110592);
    // fc1 + gelu -> Qkv (768 cols)
    mgemm<128, 128, 2, 0><<<dim3(6, 864, 1), 256, 0, stream>>>(
        Hbuf, 192, 0, W1, 192, 0, Qkv, 768, 0, fc1_b, 192, nullptr, nullptr);
    // fc2 + resid -> out (fp32, in-place resid)
    mgemm<128, 64, 3, 0><<<dim3(3, 864, 1), 256, 0, stream>>>(
        Qkv, 768, 0, W2, 768, 0, nullptr, 192, 0, fc2_b, 768, out, out);
}

// Round 5
// 820.022 us; speedup vs baseline: 25.9532x; 1.0124x over previous
//
#include <hip/hip_runtime.h>

typedef __bf16 bf16_t;
typedef __attribute__((ext_vector_type(8))) __bf16 bf16x8;
typedef __attribute__((ext_vector_type(4))) float f32x4;

__device__ __forceinline__ float gelu_exact(float x) {
    return 0.5f * x * (1.0f + erff(x * 0.70710678118654752f));
}

// ---------- MFMA bf16 GEMM, m97 structure + BK=64 + T2 XOR swizzle ----------
// C[m][n] = sum_k A[m][k] * B[n][k]  (both operands K-major, bf16)
// 256 threads = 4 waves in 2x2 grid; each wave owns (BM/2)x(BN/2);
// 16x16x32 bf16 MFMA; global_load_lds width-16 into linear LDS with
// pre-swizzled SOURCE columns (chunk ^= row&7); same XOR on ds_read side.
// EPI: 0 = plain bf16 | 1 = +bias bf16 | 2 = gelu(+bias) bf16 | 3 = fp32 resid+acc+bias
// SWZ: 1 = XCD-chunked block remap (grid size must be divisible by 8)
template<int BM, int BN, int EPI, int SWZ>
__global__ __launch_bounds__(256)
void mgemm(const bf16_t* __restrict__ A, int lda, long aBatch,
           const bf16_t* __restrict__ B, int ldb, long bBatch,
           bf16_t* __restrict__ C, int ldc, long cBatch,
           const float* __restrict__ bias, int K,
           float* __restrict__ Cf, const float* __restrict__ resid)
{
    constexpr int MR = BM / 32;   // 16x16 frags per wave, M dir
    constexpr int NR = BN / 32;   // 16x16 frags per wave, N dir
    __shared__ __align__(16) bf16_t As[BM * 64];
    __shared__ __align__(16) bf16_t Bs[BN * 64];
    const int t    = threadIdx.x;
    const int w    = t >> 6;
    const int lane = t & 63;
    const int wr   = w >> 1, wc = w & 1;

    unsigned bx = blockIdx.x, by = blockIdx.y, bz = blockIdx.z;
    if constexpr (SWZ) {
        const unsigned gx = gridDim.x, gy = gridDim.y, gz = gridDim.z;
        unsigned lin = (bz * gy + by) * gx + bx;
        const unsigned cpx = (gx * gy * gz) >> 3;   // grid % 8 == 0 at all call sites
        lin = (lin & 7) * cpx + (lin >> 3);
        bx = lin % gx; lin /= gx;
        by = lin % gy; bz = lin / gy;
    }

    const long n0 = (long)bx * BN;
    const long m0 = (long)by * BM;
    A += (long)bz * aBatch;
    B += (long)bz * bBatch;
    if constexpr (EPI != 3) C += (long)bz * cBatch;

    f32x4 acc[MR][NR] = {};

    // staging: issue chunk c covers rows c*32 + (t>>3); lane's 16B goes to
    // linear LDS elem offset c*2048 + t*8, i.e. (row, chunk t&7).
    // Source column pre-swizzled so that LDS (row, ch) holds global (row, ch^(row&7)).
    const int srow8 = t >> 3;                              // 0..31 row-in-issue
    const int schunk = (t & 7) ^ (srow8 & 7);              // source k-chunk (8 bf16)
    const int lrow = lane & 15;
    const int kq4  = lane >> 4;                            // 0..3 k-quarter within 32

    for (int k0 = 0; k0 < K; k0 += 64) {
        #pragma unroll
        for (int c = 0; c < BM / 32; ++c) {
            const bf16_t* src = A + (m0 + c * 32 + srow8) * (long)lda + (k0 + schunk * 8);
            __builtin_amdgcn_global_load_lds(
                (__attribute__((address_space(1))) void*)(bf16_t*)src,
                (__attribute__((address_space(3))) void*)(As + c * 2048 + w * 512),
                16, 0, 0);
        }
        #pragma unroll
        for (int c = 0; c < BN / 32; ++c) {
            const bf16_t* src = B + (n0 + c * 32 + srow8) * (long)ldb + (k0 + schunk * 8);
            __builtin_amdgcn_global_load_lds(
                (__attribute__((address_space(1))) void*)(bf16_t*)src,
                (__attribute__((address_space(3))) void*)(Bs + c * 2048 + w * 512),
                16, 0, 0);
        }
        __syncthreads();

        // fragments: lane holds row (l&15), k = ks*32 + (l>>4)*8 .. +7
        bf16x8 af[MR][2], bfr[NR][2];
        #pragma unroll
        for (int i = 0; i < MR; ++i) {
            const int row = wr * (BM / 2) + i * 16 + lrow;
            #pragma unroll
            for (int ks = 0; ks < 2; ++ks) {
                const int ch = (ks * 4 + kq4) ^ (row & 7);
                af[i][ks] = *(const bf16x8*)(As + row * 64 + ch * 8);
            }
        }
        #pragma unroll
        for (int j = 0; j < NR; ++j) {
            const int row = wc * (BN / 2) + j * 16 + lrow;
            #pragma unroll
            for (int ks = 0; ks < 2; ++ks) {
                const int ch = (ks * 4 + kq4) ^ (row & 7);
                bfr[j][ks] = *(const bf16x8*)(Bs + row * 64 + ch * 8);
            }
        }
        #pragma unroll
        for (int ks = 0; ks < 2; ++ks)
            #pragma unroll
            for (int i = 0; i < MR; ++i)
                #pragma unroll
                for (int j = 0; j < NR; ++j)
                    acc[i][j] = __builtin_amdgcn_mfma_f32_16x16x32_bf16(
                        af[i][ks], bfr[j][ks], acc[i][j], 0, 0, 0);
        __syncthreads();
    }

    // D mapping col=lane&15, row=(lane>>4)*4+reg (m89/m91-verified)
    const int ccol  = lane & 15;
    const int crow4 = (lane >> 4) * 4;
    #pragma unroll
    for (int i = 0; i < MR; ++i) {
        long rowb = m0 + wr * (BM / 2) + i * 16 + crow4;
        #pragma unroll
        for (int j = 0; j < NR; ++j) {
            long col = n0 + wc * (BN / 2) + j * 16 + ccol;
            #pragma unroll
            for (int r = 0; r < 4; ++r) {
                float v = acc[i][j][r];
                long row = rowb + r;
                if constexpr (EPI == 0) {
                    C[row * ldc + col] = (bf16_t)v;
                } else if constexpr (EPI == 1) {
                    C[row * ldc + col] = (bf16_t)(v + bias[col]);
                } else if constexpr (EPI == 2) {
                    C[row * ldc + col] = (bf16_t)gelu_exact(v + bias[col]);
                } else {
                    long idx = row * ldc + col;
                    Cf[idx] = resid[idx] + v + bias[col];
                }
            }
        }
    }
}

// Vt[h][e][m] = V[h][m][e],  V[h][m][e] = Y[m*27648 + 18432 + h*1536 + e]
// bf16x8 loads/stores through XOR-swizzled LDS tile (chunk ^= row>>3, stride 80).
__global__ __launch_bounds__(256)
void transpose_v(const bf16_t* __restrict__ Y, bf16_t* __restrict__ Vt)
{
    __shared__ bf16_t tile[64][80];
    const int h  = blockIdx.z;
    const int e0 = blockIdx.x * 64;
    const int m0 = blockIdx.y * 64;
    const int t  = threadIdx.x;
    const int lr = t >> 3;          // 0..31
    const int lc8 = t & 7;          // chunk index 0..7

    #pragma unroll
    for (int i = 0; i < 64; i += 32) {
        int row = lr + i;           // m-local
        bf16x8 vv = *(const bf16x8*)(Y + (long)(m0 + row) * 27648 + 18432 + h * 1536 + e0 + lc8 * 8);
        int cs = lc8 ^ (row >> 3);  // swizzled e-chunk
        *(bf16x8*)&tile[row][cs * 8] = vv;
    }
    __syncthreads();
    #pragma unroll
    for (int i = 0; i < 64; i += 32) {
        int er = lr + i;            // e-local
        bf16x8 vv;
        #pragma unroll
        for (int j = 0; j < 8; ++j) {
            int row = lc8 * 8 + j;  // m-local
            int cs = (er >> 3) ^ lc8;   // (row>>3) == lc8
            vv[j] = tile[row][cs * 8 + (er & 7)];
        }
        *(bf16x8*)(Vt + ((long)h * 1536 + e0 + er) * 2304 + m0 + lc8 * 8) = vv;
    }
}

// LayerNorm: one WAVE per 192-row, shfl reductions, zero barriers. fp32 in -> bf16 out.
__global__ __launch_bounds__(256)
void ln_fast(const float* __restrict__ x, const float* __restrict__ g,
             const float* __restrict__ b, bf16_t* __restrict__ o, int nrows)
{
    const int lane = threadIdx.x & 63;
    const int wave = threadIdx.x >> 6;
    const float g0 = g[lane], g1 = g[lane + 64], g2 = g[lane + 128];
    const float b0 = b[lane], b1 = b[lane + 64], b2 = b[lane + 128];
    for (long row = (long)blockIdx.x * 4 + wave; row < nrows; row += (long)gridDim.x * 4) {
        const float* xr = x + row * 192;
        float v0 = xr[lane], v1 = xr[lane + 64], v2 = xr[lane + 128];
        float s  = v0 + v1 + v2;
        float ss = v0 * v0 + v1 * v1 + v2 * v2;
        #pragma unroll
        for (int d = 32; d > 0; d >>= 1) {
            s  += __shfl_xor(s, d);
            ss += __shfl_xor(ss, d);
        }
        float mean = s * (1.f / 192.f);
        float var  = ss * (1.f / 192.f) - mean * mean;
        float rs   = rsqrtf(var + 1e-5f);
        bf16_t* orow = o + row * 192;
        orow[lane]       = (bf16_t)((v0 - mean) * rs * g0 + b0);
        orow[lane + 64]  = (bf16_t)((v1 - mean) * rs * g1 + b1);
        orow[lane + 128] = (bf16_t)((v2 - mean) * rs * g2 + b2);
    }
}

// softmax over 2304 bf16 logits (scale folded), in place. Wave shfl + 4-entry LDS, 2 barriers.
__global__ __launch_bounds__(256)
void softmax_fast(bf16_t* __restrict__ S)
{
    const float SC = 0.17677669529663687f;  // 32^-0.5
    __shared__ float wmax[4], wsum[4];
    const long base = (long)blockIdx.x * 2304;
    const int t = threadIdx.x;
    const int lane = t & 63, w = t >> 6;
    float v[9];
    float mx = -1e30f;
    #pragma unroll
    for (int i = 0; i < 9; ++i) {
        v[i] = (float)S[base + t + i * 256] * SC;
        mx = fmaxf(mx, v[i]);
    }
    #pragma unroll
    for (int d = 32; d > 0; d >>= 1) mx = fmaxf(mx, __shfl_xor(mx, d));
    if (lane == 0) wmax[w] = mx;
    __syncthreads();
    mx = fmaxf(fmaxf(wmax[0], wmax[1]), fmaxf(wmax[2], wmax[3]));
    float sum = 0.f;
    #pragma unroll
    for (int i = 0; i < 9; ++i) { v[i] = __expf(v[i] - mx); sum += v[i]; }
    #pragma unroll
    for (int d = 32; d > 0; d >>= 1) sum += __shfl_xor(sum, d);
    if (lane == 0) wsum[w] = sum;
    __syncthreads();
    const float inv = 1.f / (wsum[0] + wsum[1] + wsum[2] + wsum[3]);
    #pragma unroll
    for (int i = 0; i < 9; ++i) S[base + t + i * 256] = (bf16_t)(v[i] * inv);
}

// all four weight casts in one launch (segments concatenated)
__global__ __launch_bounds__(256)
void cast_all(const float* __restrict__ w0, const float* __restrict__ w1,
              const float* __restrict__ w2, const float* __restrict__ w3,
              bf16_t* __restrict__ o0, bf16_t* __restrict__ o1,
              bf16_t* __restrict__ o2, bf16_t* __restrict__ o3)
{
    // sizes: 110592, 36864, 147456, 147456  (cum: 110592, 147456, 294912, 442368)
    int i = blockIdx.x * 256 + threadIdx.x;
    if (i < 110592)       o0[i] = (bf16_t)w0[i];
    else if (i < 147456)  o1[i - 110592] = (bf16_t)w1[i - 110592];
    else if (i < 294912)  o2[i - 147456] = (bf16_t)w2[i - 147456];
    else if (i < 442368)  o3[i - 294912] = (bf16_t)w3[i - 294912];
}

extern "C" void kernel_launch(void* const* d_in, const int* in_sizes, int n_in,
                              void* d_out, int out_size, void* d_ws, size_t ws_size,
                              hipStream_t stream)
{
    (void)in_sizes; (void)n_in; (void)out_size; (void)ws_size;
    const float* x      = (const float*)d_in[0];
    const float* n1g    = (const float*)d_in[1];
    const float* n1b    = (const float*)d_in[2];
    const float* qkv_w  = (const float*)d_in[3];
    const float* qkv_b  = (const float*)d_in[4];
    const float* proj_w = (const float*)d_in[5];
    const float* proj_b = (const float*)d_in[6];
    const float* n2g    = (const float*)d_in[7];
    const float* n2b    = (const float*)d_in[8];
    const float* fc1_w  = (const float*)d_in[9];
    const float* fc1_b  = (const float*)d_in[10];
    const float* fc2_w  = (const float*)d_in[11];
    const float* fc2_b  = (const float*)d_in[12];
    float* out = (float*)d_out;

    char* ws = (char*)d_ws;
    size_t off = 0;
    auto alloc = [&](size_t nbytes) -> void* {
        off = (off + 255) & ~(size_t)255;
        void* p = ws + off;
        off += nbytes;
        return p;
    };

    bf16_t* Wq   = (bf16_t*)alloc((size_t)576 * 192 * 2);
    bf16_t* Wp   = (bf16_t*)alloc((size_t)192 * 192 * 2);
    bf16_t* W1   = (bf16_t*)alloc((size_t)768 * 192 * 2);
    bf16_t* W2   = (bf16_t*)alloc((size_t)192 * 768 * 2);
    bf16_t* Hbuf = (bf16_t*)alloc((size_t)110592 * 192 * 2);   // ln1 out -> O -> ln2 out
    bf16_t* Qkv  = (bf16_t*)alloc((size_t)110592 * 768 * 2);   // qkv(576)+Vt tail -> fc1(768)
    bf16_t* Vt   = Qkv + (size_t)110592 * 576;
    bf16_t* Sbuf = (bf16_t*)d_out;                              // 63.7 MB <= 85 MB, dead until proj

    cast_all<<<1728, 256, 0, stream>>>(qkv_w, proj_w, fc1_w, fc2_w, Wq, Wp, W1, W2);

    // LN1: x -> Hbuf (bf16)
    ln_fast<<<2048, 256, 0, stream>>>(x, n1g, n1b, Hbuf, 110592);
    // QKV: (110592x192)@(576x192)^T + b -> Qkv
    mgemm<128, 64, 1, 0><<<dim3(9, 864, 1), 256, 0, stream>>>(
        Hbuf, 192, 0, Wq, 192, 0, Qkv, 576, 0, qkv_b, 192, nullptr, nullptr);
    // Vt[h][e][m] = V[h][m][e]
    transpose_v<<<dim3(24, 36, 6), 256, 0, stream>>>(Qkv, Vt);
    // S = Q @ K^T per head (z=6): 2304x2304, K=1536   [grid 1944 % 8 == 0]
    mgemm<128, 128, 0, 1><<<dim3(18, 18, 6), 256, 0, stream>>>(
        Qkv, 27648, 1536, Qkv + 9216, 27648, 1536,
        Sbuf, 2304, (long)2304 * 2304, nullptr, 1536, nullptr, nullptr);
    // softmax rows (scale inside), in place
    softmax_fast<<<13824, 256, 0, stream>>>(Sbuf);
    // O = P @ Vt^T per head: 2304x1536, K=2304        [grid 1296 % 8 == 0]
    mgemm<128, 128, 0, 1><<<dim3(12, 18, 6), 256, 0, stream>>>(
        Sbuf, 2304, (long)2304 * 2304, Vt, 2304, (long)1536 * 2304,
        Hbuf, 9216, 1536, nullptr, 2304, nullptr, nullptr);
    // x1 = x + O @ Wp^T + pb -> out (fp32)
    mgemm<128, 64, 3, 0><<<dim3(3, 864, 1), 256, 0, stream>>>(
        Hbuf, 192, 0, Wp, 192, 0, nullptr, 192, 0, proj_b, 192, out, x);
    // LN2: x1 -> Hbuf (bf16)
    ln_fast<<<2048, 256, 0, stream>>>(out, n2g, n2b, Hbuf, 110592);
    // fc1 + gelu -> Qkv (768 cols)
    mgemm<128, 128, 2, 0><<<dim3(6, 864, 1), 256, 0, stream>>>(
        Hbuf, 192, 0, W1, 192, 0, Qkv, 768, 0, fc1_b, 192, nullptr, nullptr);
    // fc2 + resid -> out (fp32, in-place resid)
    mgemm<128, 64, 3, 0><<<dim3(3, 864, 1), 256, 0, stream>>>(
        Qkv, 768, 0, W2, 768, 0, nullptr, 192, 0, fc2_b, 768, out, out);
}

// Round 6
// 795.139 us; speedup vs baseline: 26.7654x; 1.0313x over previous
//
#include <hip/hip_runtime.h>

typedef __bf16 bf16_t;
typedef __attribute__((ext_vector_type(8))) __bf16 bf16x8;
typedef __attribute__((ext_vector_type(4))) float f32x4;

__device__ __forceinline__ float gelu_exact(float x) {
    return 0.5f * x * (1.0f + erff(x * 0.70710678118654752f));
}

// ---------- MFMA bf16 GEMM: BK=64, T2 XOR swizzle, double-buffered prefetch ----------
// C[m][n] = sum_k A[m][k] * B[n][k]  (both operands K-major, bf16)
// 256 threads = 4 waves in 2x2 grid; each wave owns (BM/2)x(BN/2);
// 16x16x32 bf16 MFMA; global_load_lds width-16 into linear LDS with
// pre-swizzled SOURCE columns (chunk ^= row&7); same XOR on ds_read side.
// K-loop = T3-minimum 2-phase: STAGE(next) -> ds_read(cur)+MFMA -> barrier.
// EPI: 0 = plain bf16 | 1 = +bias bf16 | 2 = gelu(+bias) bf16 | 3 = fp32 resid+acc+bias
// SWZ: 1 = XCD-chunked block remap (grid size must be divisible by 8)
template<int BM, int BN, int EPI, int SWZ>
__global__ __launch_bounds__(256)
void mgemm(const bf16_t* __restrict__ A, int lda, long aBatch,
           const bf16_t* __restrict__ B, int ldb, long bBatch,
           bf16_t* __restrict__ C, int ldc, long cBatch,
           const float* __restrict__ bias, int K,
           float* __restrict__ Cf, const float* __restrict__ resid)
{
    constexpr int MR = BM / 32;   // 16x16 frags per wave, M dir
    constexpr int NR = BN / 32;   // 16x16 frags per wave, N dir
    __shared__ __align__(16) bf16_t As[2][BM * 64];
    __shared__ __align__(16) bf16_t Bs[2][BN * 64];
    const int t    = threadIdx.x;
    const int w    = t >> 6;
    const int lane = t & 63;
    const int wr   = w >> 1, wc = w & 1;

    unsigned bx = blockIdx.x, by = blockIdx.y, bz = blockIdx.z;
    if constexpr (SWZ) {
        const unsigned gx = gridDim.x, gy = gridDim.y, gz = gridDim.z;
        unsigned lin = (bz * gy + by) * gx + bx;
        const unsigned cpx = (gx * gy * gz) >> 3;   // grid % 8 == 0 at all call sites
        lin = (lin & 7) * cpx + (lin >> 3);
        bx = lin % gx; lin /= gx;
        by = lin % gy; bz = lin / gy;
    }

    const long n0 = (long)bx * BN;
    const long m0 = (long)by * BM;
    A += (long)bz * aBatch;
    B += (long)bz * bBatch;
    if constexpr (EPI != 3) C += (long)bz * cBatch;

    f32x4 acc[MR][NR] = {};

    // staging: issue chunk c covers rows c*32 + (t>>3); lane's 16B goes to
    // linear LDS elem offset c*2048 + t*8, i.e. (row, chunk t&7).
    // Source column pre-swizzled so LDS (row, ch) holds global (row, ch^(row&7)).
    const int srow8  = t >> 3;                   // 0..31 row-in-issue
    const int schunk = (t & 7) ^ (srow8 & 7);    // source k-chunk (8 bf16)
    const int lrow = lane & 15;
    const int kq4  = lane >> 4;                  // 0..3 k-quarter within 32

    auto stage = [&](int buf, int k0) {
        #pragma unroll
        for (int c = 0; c < BM / 32; ++c) {
            const bf16_t* src = A + (m0 + c * 32 + srow8) * (long)lda + (k0 + schunk * 8);
            __builtin_amdgcn_global_load_lds(
                (__attribute__((address_space(1))) void*)(bf16_t*)src,
                (__attribute__((address_space(3))) void*)(As[buf] + c * 2048 + w * 512),
                16, 0, 0);
        }
        #pragma unroll
        for (int c = 0; c < BN / 32; ++c) {
            const bf16_t* src = B + (n0 + c * 32 + srow8) * (long)ldb + (k0 + schunk * 8);
            __builtin_amdgcn_global_load_lds(
                (__attribute__((address_space(1))) void*)(bf16_t*)src,
                (__attribute__((address_space(3))) void*)(Bs[buf] + c * 2048 + w * 512),
                16, 0, 0);
        }
    };

    const int nt = K >> 6;          // K / 64; all call sites K % 64 == 0
    stage(0, 0);
    __syncthreads();                // drain prologue staging
    int cur = 0;
    for (int kt = 0; kt < nt; ++kt) {
        if (kt + 1 < nt) stage(cur ^ 1, (kt + 1) << 6);   // prefetch next K-tile

        // fragments: lane holds row (l&15), k = ks*32 + (l>>4)*8 .. +7
        bf16x8 af[MR][2], bfr[NR][2];
        #pragma unroll
        for (int i = 0; i < MR; ++i) {
            const int row = wr * (BM / 2) + i * 16 + lrow;
            #pragma unroll
            for (int ks = 0; ks < 2; ++ks) {
                const int ch = (ks * 4 + kq4) ^ (row & 7);
                af[i][ks] = *(const bf16x8*)(As[cur] + row * 64 + ch * 8);
            }
        }
        #pragma unroll
        for (int j = 0; j < NR; ++j) {
            const int row = wc * (BN / 2) + j * 16 + lrow;
            #pragma unroll
            for (int ks = 0; ks < 2; ++ks) {
                const int ch = (ks * 4 + kq4) ^ (row & 7);
                bfr[j][ks] = *(const bf16x8*)(Bs[cur] + row * 64 + ch * 8);
            }
        }
        #pragma unroll
        for (int ks = 0; ks < 2; ++ks)
            #pragma unroll
            for (int i = 0; i < MR; ++i)
                #pragma unroll
                for (int j = 0; j < NR; ++j)
                    acc[i][j] = __builtin_amdgcn_mfma_f32_16x16x32_bf16(
                        af[i][ks], bfr[j][ks], acc[i][j], 0, 0, 0);

        __syncthreads();            // one barrier per K-step: drains prefetch + read-reuse fence
        cur ^= 1;
    }

    // D mapping col=lane&15, row=(lane>>4)*4+reg (m89/m91-verified)
    const int ccol  = lane & 15;
    const int crow4 = (lane >> 4) * 4;
    #pragma unroll
    for (int i = 0; i < MR; ++i) {
        long rowb = m0 + wr * (BM / 2) + i * 16 + crow4;
        #pragma unroll
        for (int j = 0; j < NR; ++j) {
            long col = n0 + wc * (BN / 2) + j * 16 + ccol;
            #pragma unroll
            for (int r = 0; r < 4; ++r) {
                float v = acc[i][j][r];
                long row = rowb + r;
                if constexpr (EPI == 0) {
                    C[row * ldc + col] = (bf16_t)v;
                } else if constexpr (EPI == 1) {
                    C[row * ldc + col] = (bf16_t)(v + bias[col]);
                } else if constexpr (EPI == 2) {
                    C[row * ldc + col] = (bf16_t)gelu_exact(v + bias[col]);
                } else {
                    long idx = row * ldc + col;
                    Cf[idx] = resid[idx] + v + bias[col];
                }
            }
        }
    }
}

// Vt[h][e][m] = V[h][m][e],  V[h][m][e] = Y[m*27648 + 18432 + h*1536 + e]
// bf16x8 loads/stores through XOR-swizzled LDS tile (chunk ^= row>>3, stride 80).
__global__ __launch_bounds__(256)
void transpose_v(const bf16_t* __restrict__ Y, bf16_t* __restrict__ Vt)
{
    __shared__ bf16_t tile[64][80];
    const int h  = blockIdx.z;
    const int e0 = blockIdx.x * 64;
    const int m0 = blockIdx.y * 64;
    const int t  = threadIdx.x;
    const int lr = t >> 3;          // 0..31
    const int lc8 = t & 7;          // chunk index 0..7

    #pragma unroll
    for (int i = 0; i < 64; i += 32) {
        int row = lr + i;           // m-local
        bf16x8 vv = *(const bf16x8*)(Y + (long)(m0 + row) * 27648 + 18432 + h * 1536 + e0 + lc8 * 8);
        int cs = lc8 ^ (row >> 3);  // swizzled e-chunk
        *(bf16x8*)&tile[row][cs * 8] = vv;
    }
    __syncthreads();
    #pragma unroll
    for (int i = 0; i < 64; i += 32) {
        int er = lr + i;            // e-local
        bf16x8 vv;
        #pragma unroll
        for (int j = 0; j < 8; ++j) {
            int row = lc8 * 8 + j;  // m-local
            int cs = (er >> 3) ^ lc8;   // (row>>3) == lc8
            vv[j] = tile[row][cs * 8 + (er & 7)];
        }
        *(bf16x8*)(Vt + ((long)h * 1536 + e0 + er) * 2304 + m0 + lc8 * 8) = vv;
    }
}

// LayerNorm: one WAVE per 192-row, shfl reductions, zero barriers. fp32 in -> bf16 out.
__global__ __launch_bounds__(256)
void ln_fast(const float* __restrict__ x, const float* __restrict__ g,
             const float* __restrict__ b, bf16_t* __restrict__ o, int nrows)
{
    const int lane = threadIdx.x & 63;
    const int wave = threadIdx.x >> 6;
    const float g0 = g[lane], g1 = g[lane + 64], g2 = g[lane + 128];
    const float b0 = b[lane], b1 = b[lane + 64], b2 = b[lane + 128];
    for (long row = (long)blockIdx.x * 4 + wave; row < nrows; row += (long)gridDim.x * 4) {
        const float* xr = x + row * 192;
        float v0 = xr[lane], v1 = xr[lane + 64], v2 = xr[lane + 128];
        float s  = v0 + v1 + v2;
        float ss = v0 * v0 + v1 * v1 + v2 * v2;
        #pragma unroll
        for (int d = 32; d > 0; d >>= 1) {
            s  += __shfl_xor(s, d);
            ss += __shfl_xor(ss, d);
        }
        float mean = s * (1.f / 192.f);
        float var  = ss * (1.f / 192.f) - mean * mean;
        float rs   = rsqrtf(var + 1e-5f);
        bf16_t* orow = o + row * 192;
        orow[lane]       = (bf16_t)((v0 - mean) * rs * g0 + b0);
        orow[lane + 64]  = (bf16_t)((v1 - mean) * rs * g1 + b1);
        orow[lane + 128] = (bf16_t)((v2 - mean) * rs * g2 + b2);
    }
}

// softmax over 2304 bf16 logits (scale folded), in place. Wave shfl + 4-entry LDS, 2 barriers.
__global__ __launch_bounds__(256)
void softmax_fast(bf16_t* __restrict__ S)
{
    const float SC = 0.17677669529663687f;  // 32^-0.5
    __shared__ float wmax[4], wsum[4];
    const long base = (long)blockIdx.x * 2304;
    const int t = threadIdx.x;
    const int lane = t & 63, w = t >> 6;
    float v[9];
    float mx = -1e30f;
    #pragma unroll
    for (int i = 0; i < 9; ++i) {
        v[i] = (float)S[base + t + i * 256] * SC;
        mx = fmaxf(mx, v[i]);
    }
    #pragma unroll
    for (int d = 32; d > 0; d >>= 1) mx = fmaxf(mx, __shfl_xor(mx, d));
    if (lane == 0) wmax[w] = mx;
    __syncthreads();
    mx = fmaxf(fmaxf(wmax[0], wmax[1]), fmaxf(wmax[2], wmax[3]));
    float sum = 0.f;
    #pragma unroll
    for (int i = 0; i < 9; ++i) { v[i] = __expf(v[i] - mx); sum += v[i]; }
    #pragma unroll
    for (int d = 32; d > 0; d >>= 1) sum += __shfl_xor(sum, d);
    if (lane == 0) wsum[w] = sum;
    __syncthreads();
    const float inv = 1.f / (wsum[0] + wsum[1] + wsum[2] + wsum[3]);
    #pragma unroll
    for (int i = 0; i < 9; ++i) S[base + t + i * 256] = (bf16_t)(v[i] * inv);
}

// all four weight casts in one launch (segments concatenated)
__global__ __launch_bounds__(256)
void cast_all(const float* __restrict__ w0, const float* __restrict__ w1,
              const float* __restrict__ w2, const float* __restrict__ w3,
              bf16_t* __restrict__ o0, bf16_t* __restrict__ o1,
              bf16_t* __restrict__ o2, bf16_t* __restrict__ o3)
{
    // sizes: 110592, 36864, 147456, 147456  (cum: 110592, 147456, 294912, 442368)
    int i = blockIdx.x * 256 + threadIdx.x;
    if (i < 110592)       o0[i] = (bf16_t)w0[i];
    else if (i < 147456)  o1[i - 110592] = (bf16_t)w1[i - 110592];
    else if (i < 294912)  o2[i - 147456] = (bf16_t)w2[i - 147456];
    else if (i < 442368)  o3[i - 294912] = (bf16_t)w3[i - 294912];
}

extern "C" void kernel_launch(void* const* d_in, const int* in_sizes, int n_in,
                              void* d_out, int out_size, void* d_ws, size_t ws_size,
                              hipStream_t stream)
{
    (void)in_sizes; (void)n_in; (void)out_size; (void)ws_size;
    const float* x      = (const float*)d_in[0];
    const float* n1g    = (const float*)d_in[1];
    const float* n1b    = (const float*)d_in[2];
    const float* qkv_w  = (const float*)d_in[3];
    const float* qkv_b  = (const float*)d_in[4];
    const float* proj_w = (const float*)d_in[5];
    const float* proj_b = (const float*)d_in[6];
    const float* n2g    = (const float*)d_in[7];
    const float* n2b    = (const float*)d_in[8];
    const float* fc1_w  = (const float*)d_in[9];
    const float* fc1_b  = (const float*)d_in[10];
    const float* fc2_w  = (const float*)d_in[11];
    const float* fc2_b  = (const float*)d_in[12];
    float* out = (float*)d_out;

    char* ws = (char*)d_ws;
    size_t off = 0;
    auto alloc = [&](size_t nbytes) -> void* {
        off = (off + 255) & ~(size_t)255;
        void* p = ws + off;
        off += nbytes;
        return p;
    };

    bf16_t* Wq   = (bf16_t*)alloc((size_t)576 * 192 * 2);
    bf16_t* Wp   = (bf16_t*)alloc((size_t)192 * 192 * 2);
    bf16_t* W1   = (bf16_t*)alloc((size_t)768 * 192 * 2);
    bf16_t* W2   = (bf16_t*)alloc((size_t)192 * 768 * 2);
    bf16_t* Hbuf = (bf16_t*)alloc((size_t)110592 * 192 * 2);   // ln1 out -> O -> ln2 out
    bf16_t* Qkv  = (bf16_t*)alloc((size_t)110592 * 768 * 2);   // qkv(576)+Vt tail -> fc1(768)
    bf16_t* Vt   = Qkv + (size_t)110592 * 576;
    bf16_t* Sbuf = (bf16_t*)d_out;                              // 63.7 MB <= 85 MB, dead until proj

    cast_all<<<1728, 256, 0, stream>>>(qkv_w, proj_w, fc1_w, fc2_w, Wq, Wp, W1, W2);

    // LN1: x -> Hbuf (bf16)
    ln_fast<<<2048, 256, 0, stream>>>(x, n1g, n1b, Hbuf, 110592);
    // QKV: (110592x192)@(576x192)^T + b -> Qkv
    mgemm<128, 64, 1, 0><<<dim3(9, 864, 1), 256, 0, stream>>>(
        Hbuf, 192, 0, Wq, 192, 0, Qkv, 576, 0, qkv_b, 192, nullptr, nullptr);
    // Vt[h][e][m] = V[h][m][e]
    transpose_v<<<dim3(24, 36, 6), 256, 0, stream>>>(Qkv, Vt);
    // S = Q @ K^T per head (z=6): 2304x2304, K=1536   [grid 1944 % 8 == 0]
    mgemm<128, 128, 0, 1><<<dim3(18, 18, 6), 256, 0, stream>>>(
        Qkv, 27648, 1536, Qkv + 9216, 27648, 1536,
        Sbuf, 2304, (long)2304 * 2304, nullptr, 1536, nullptr, nullptr);
    // softmax rows (scale inside), in place
    softmax_fast<<<13824, 256, 0, stream>>>(Sbuf);
    // O = P @ Vt^T per head: 2304x1536, K=2304        [grid 1296 % 8 == 0]
    mgemm<128, 128, 0, 1><<<dim3(12, 18, 6), 256, 0, stream>>>(
        Sbuf, 2304, (long)2304 * 2304, Vt, 2304, (long)1536 * 2304,
        Hbuf, 9216, 1536, nullptr, 2304, nullptr, nullptr);
    // x1 = x + O @ Wp^T + pb -> out (fp32)
    mgemm<128, 64, 3, 0><<<dim3(3, 864, 1), 256, 0, stream>>>(
        Hbuf, 192, 0, Wp, 192, 0, nullptr, 192, 0, proj_b, 192, out, x);
    // LN2: x1 -> Hbuf (bf16)
    ln_fast<<<2048, 256, 0, stream>>>(out, n2g, n2b, Hbuf, 110592);
    // fc1 + gelu -> Qkv (768 cols)
    mgemm<128, 128, 2, 0><<<dim3(6, 864, 1), 256, 0, stream>>>(
        Hbuf, 192, 0, W1, 192, 0, Qkv, 768, 0, fc1_b, 192, nullptr, nullptr);
    // fc2 + resid -> out (fp32, in-place resid)
    mgemm<128, 64, 3, 0><<<dim3(3, 864, 1), 256, 0, stream>>>(
        Qkv, 768, 0, W2, 768, 0, nullptr, 192, 0, fc2_b, 768, out, out);
}

// Round 7
// 792.214 us; speedup vs baseline: 26.8642x; 1.0037x over previous
//
#include <hip/hip_runtime.h>

typedef __bf16 bf16_t;
typedef __attribute__((ext_vector_type(8))) __bf16 bf16x8;
typedef __attribute__((ext_vector_type(4))) float f32x4;

__device__ __forceinline__ float gelu_exact(float x) {
    return 0.5f * x * (1.0f + erff(x * 0.70710678118654752f));
}

// ---------- MFMA bf16 GEMM: BK=64, T2 XOR swizzle, dbuf + counted-vmcnt (T4) ----------
// C[m][n] = sum_k A[m][k] * B[n][k]  (both operands K-major, bf16)
// 256 threads = 4 waves in 2x2 grid; each wave owns (BM/2)x(BN/2);
// 16x16x32 bf16 MFMA; global_load_lds width-16 into linear LDS with
// pre-swizzled SOURCE columns (chunk ^= row&7); same XOR on ds_read side.
// K-loop: stage(T+1) -> vmcnt(LPT) [T landed, T+1 in flight] -> barrier ->
//         ds_read(cur)+MFMA -> lgkmcnt(0) -> barrier. Never drains vmcnt to 0
//         in steady state (the T4 ingredient the old __syncthreads destroyed).
// EPI: 0 = plain bf16 | 1 = +bias bf16 | 2 = gelu(+bias) bf16 | 3 = fp32 resid+acc+bias
// SWZ: 1 = XCD-chunked block remap (grid size must be divisible by 8)
template<int BM, int BN, int EPI, int SWZ>
__global__ __launch_bounds__(256)
void mgemm(const bf16_t* __restrict__ A, int lda, long aBatch,
           const bf16_t* __restrict__ B, int ldb, long bBatch,
           bf16_t* __restrict__ C, int ldc, long cBatch,
           const float* __restrict__ bias, int K,
           float* __restrict__ Cf, const float* __restrict__ resid)
{
    constexpr int MR = BM / 32;   // 16x16 frags per wave, M dir
    constexpr int NR = BN / 32;   // 16x16 frags per wave, N dir
    constexpr int LPT = BM / 32 + BN / 32;   // gload_lds per thread per K-tile
    __shared__ __align__(16) bf16_t As[2][BM * 64];
    __shared__ __align__(16) bf16_t Bs[2][BN * 64];
    const int t    = threadIdx.x;
    const int w    = t >> 6;
    const int lane = t & 63;
    const int wr   = w >> 1, wc = w & 1;

    unsigned bx = blockIdx.x, by = blockIdx.y, bz = blockIdx.z;
    if constexpr (SWZ) {
        const unsigned gx = gridDim.x, gy = gridDim.y, gz = gridDim.z;
        unsigned lin = (bz * gy + by) * gx + bx;
        const unsigned cpx = (gx * gy * gz) >> 3;   // grid % 8 == 0 at all call sites
        lin = (lin & 7) * cpx + (lin >> 3);
        bx = lin % gx; lin /= gx;
        by = lin % gy; bz = lin / gy;
    }

    const long n0 = (long)bx * BN;
    const long m0 = (long)by * BM;
    A += (long)bz * aBatch;
    B += (long)bz * bBatch;
    if constexpr (EPI != 3) C += (long)bz * cBatch;

    f32x4 acc[MR][NR] = {};

    // staging: issue chunk c covers rows c*32 + (t>>3); lane's 16B goes to
    // linear LDS elem offset c*2048 + t*8, i.e. (row, chunk t&7).
    // Source column pre-swizzled so LDS (row, ch) holds global (row, ch^(row&7)).
    const int srow8  = t >> 3;                   // 0..31 row-in-issue
    const int schunk = (t & 7) ^ (srow8 & 7);    // source k-chunk (8 bf16)
    const int lrow = lane & 15;
    const int kq4  = lane >> 4;                  // 0..3 k-quarter within 32

    auto stage = [&](int buf, int k0) {
        #pragma unroll
        for (int c = 0; c < BM / 32; ++c) {
            const bf16_t* src = A + (m0 + c * 32 + srow8) * (long)lda + (k0 + schunk * 8);
            __builtin_amdgcn_global_load_lds(
                (__attribute__((address_space(1))) void*)(bf16_t*)src,
                (__attribute__((address_space(3))) void*)(As[buf] + c * 2048 + w * 512),
                16, 0, 0);
        }
        #pragma unroll
        for (int c = 0; c < BN / 32; ++c) {
            const bf16_t* src = B + (n0 + c * 32 + srow8) * (long)ldb + (k0 + schunk * 8);
            __builtin_amdgcn_global_load_lds(
                (__attribute__((address_space(1))) void*)(bf16_t*)src,
                (__attribute__((address_space(3))) void*)(Bs[buf] + c * 2048 + w * 512),
                16, 0, 0);
        }
    };

    const int nt = K >> 6;          // K / 64; all call sites K % 64 == 0
    stage(0, 0);
    int cur = 0;
    for (int kt = 0; kt < nt; ++kt) {
        if (kt + 1 < nt) {
            stage(cur ^ 1, (kt + 1) << 6);   // prefetch next K-tile into other buffer
            // wait only until MY tile-kt loads landed; next tile's LPT stay in flight
            if constexpr (LPT == 8)
                asm volatile("s_waitcnt vmcnt(8)" ::: "memory");
            else
                asm volatile("s_waitcnt vmcnt(6)" ::: "memory");
        } else {
            asm volatile("s_waitcnt vmcnt(0)" ::: "memory");   // final tile: full drain
        }
        __builtin_amdgcn_s_barrier();   // all waves' tile-kt loads landed

        // fragments: lane holds row (l&15), k = ks*32 + (l>>4)*8 .. +7
        bf16x8 af[MR][2], bfr[NR][2];
        #pragma unroll
        for (int i = 0; i < MR; ++i) {
            const int row = wr * (BM / 2) + i * 16 + lrow;
            #pragma unroll
            for (int ks = 0; ks < 2; ++ks) {
                const int ch = (ks * 4 + kq4) ^ (row & 7);
                af[i][ks] = *(const bf16x8*)(As[cur] + row * 64 + ch * 8);
            }
        }
        #pragma unroll
        for (int j = 0; j < NR; ++j) {
            const int row = wc * (BN / 2) + j * 16 + lrow;
            #pragma unroll
            for (int ks = 0; ks < 2; ++ks) {
                const int ch = (ks * 4 + kq4) ^ (row & 7);
                bfr[j][ks] = *(const bf16x8*)(Bs[cur] + row * 64 + ch * 8);
            }
        }
        #pragma unroll
        for (int ks = 0; ks < 2; ++ks)
            #pragma unroll
            for (int i = 0; i < MR; ++i)
                #pragma unroll
                for (int j = 0; j < NR; ++j)
                    acc[i][j] = __builtin_amdgcn_mfma_f32_16x16x32_bf16(
                        af[i][ks], bfr[j][ks], acc[i][j], 0, 0, 0);

        asm volatile("s_waitcnt lgkmcnt(0)" ::: "memory");  // pin cur-buffer reads
        __builtin_amdgcn_s_barrier();   // everyone done reading cur -> next iter may overwrite
        cur ^= 1;
    }

    // D mapping col=lane&15, row=(lane>>4)*4+reg (m89/m91-verified)
    const int ccol  = lane & 15;
    const int crow4 = (lane >> 4) * 4;
    #pragma unroll
    for (int i = 0; i < MR; ++i) {
        long rowb = m0 + wr * (BM / 2) + i * 16 + crow4;
        #pragma unroll
        for (int j = 0; j < NR; ++j) {
            long col = n0 + wc * (BN / 2) + j * 16 + ccol;
            #pragma unroll
            for (int r = 0; r < 4; ++r) {
                float v = acc[i][j][r];
                long row = rowb + r;
                if constexpr (EPI == 0) {
                    C[row * ldc + col] = (bf16_t)v;
                } else if constexpr (EPI == 1) {
                    C[row * ldc + col] = (bf16_t)(v + bias[col]);
                } else if constexpr (EPI == 2) {
                    C[row * ldc + col] = (bf16_t)gelu_exact(v + bias[col]);
                } else {
                    long idx = row * ldc + col;
                    Cf[idx] = resid[idx] + v + bias[col];
                }
            }
        }
    }
}

// Vt[h][e][m] = V[h][m][e],  V[h][m][e] = Y[m*27648 + 18432 + h*1536 + e]
// bf16x8 loads/stores through XOR-swizzled LDS tile (chunk ^= row>>3, stride 80).
__global__ __launch_bounds__(256)
void transpose_v(const bf16_t* __restrict__ Y, bf16_t* __restrict__ Vt)
{
    __shared__ bf16_t tile[64][80];
    const int h  = blockIdx.z;
    const int e0 = blockIdx.x * 64;
    const int m0 = blockIdx.y * 64;
    const int t  = threadIdx.x;
    const int lr = t >> 3;          // 0..31
    const int lc8 = t & 7;          // chunk index 0..7

    #pragma unroll
    for (int i = 0; i < 64; i += 32) {
        int row = lr + i;           // m-local
        bf16x8 vv = *(const bf16x8*)(Y + (long)(m0 + row) * 27648 + 18432 + h * 1536 + e0 + lc8 * 8);
        int cs = lc8 ^ (row >> 3);  // swizzled e-chunk
        *(bf16x8*)&tile[row][cs * 8] = vv;
    }
    __syncthreads();
    #pragma unroll
    for (int i = 0; i < 64; i += 32) {
        int er = lr + i;            // e-local
        bf16x8 vv;
        #pragma unroll
        for (int j = 0; j < 8; ++j) {
            int row = lc8 * 8 + j;  // m-local
            int cs = (er >> 3) ^ lc8;   // (row>>3) == lc8
            vv[j] = tile[row][cs * 8 + (er & 7)];
        }
        *(bf16x8*)(Vt + ((long)h * 1536 + e0 + er) * 2304 + m0 + lc8 * 8) = vv;
    }
}

// LayerNorm: one WAVE per 192-row, shfl reductions, zero barriers. fp32 in -> bf16 out.
__global__ __launch_bounds__(256)
void ln_fast(const float* __restrict__ x, const float* __restrict__ g,
             const float* __restrict__ b, bf16_t* __restrict__ o, int nrows)
{
    const int lane = threadIdx.x & 63;
    const int wave = threadIdx.x >> 6;
    const float g0 = g[lane], g1 = g[lane + 64], g2 = g[lane + 128];
    const float b0 = b[lane], b1 = b[lane + 64], b2 = b[lane + 128];
    for (long row = (long)blockIdx.x * 4 + wave; row < nrows; row += (long)gridDim.x * 4) {
        const float* xr = x + row * 192;
        float v0 = xr[lane], v1 = xr[lane + 64], v2 = xr[lane + 128];
        float s  = v0 + v1 + v2;
        float ss = v0 * v0 + v1 * v1 + v2 * v2;
        #pragma unroll
        for (int d = 32; d > 0; d >>= 1) {
            s  += __shfl_xor(s, d);
            ss += __shfl_xor(ss, d);
        }
        float mean = s * (1.f / 192.f);
        float var  = ss * (1.f / 192.f) - mean * mean;
        float rs   = rsqrtf(var + 1e-5f);
        bf16_t* orow = o + row * 192;
        orow[lane]       = (bf16_t)((v0 - mean) * rs * g0 + b0);
        orow[lane + 64]  = (bf16_t)((v1 - mean) * rs * g1 + b1);
        orow[lane + 128] = (bf16_t)((v2 - mean) * rs * g2 + b2);
    }
}

// softmax over 2304 bf16 logits (scale folded), in place. Wave shfl + 4-entry LDS, 2 barriers.
__global__ __launch_bounds__(256)
void softmax_fast(bf16_t* __restrict__ S)
{
    const float SC = 0.17677669529663687f;  // 32^-0.5
    __shared__ float wmax[4], wsum[4];
    const long base = (long)blockIdx.x * 2304;
    const int t = threadIdx.x;
    const int lane = t & 63, w = t >> 6;
    float v[9];
    float mx = -1e30f;
    #pragma unroll
    for (int i = 0; i < 9; ++i) {
        v[i] = (float)S[base + t + i * 256] * SC;
        mx = fmaxf(mx, v[i]);
    }
    #pragma unroll
    for (int d = 32; d > 0; d >>= 1) mx = fmaxf(mx, __shfl_xor(mx, d));
    if (lane == 0) wmax[w] = mx;
    __syncthreads();
    mx = fmaxf(fmaxf(wmax[0], wmax[1]), fmaxf(wmax[2], wmax[3]));
    float sum = 0.f;
    #pragma unroll
    for (int i = 0; i < 9; ++i) { v[i] = __expf(v[i] - mx); sum += v[i]; }
    #pragma unroll
    for (int d = 32; d > 0; d >>= 1) sum += __shfl_xor(sum, d);
    if (lane == 0) wsum[w] = sum;
    __syncthreads();
    const float inv = 1.f / (wsum[0] + wsum[1] + wsum[2] + wsum[3]);
    #pragma unroll
    for (int i = 0; i < 9; ++i) S[base + t + i * 256] = (bf16_t)(v[i] * inv);
}

// all four weight casts in one launch (segments concatenated)
__global__ __launch_bounds__(256)
void cast_all(const float* __restrict__ w0, const float* __restrict__ w1,
              const float* __restrict__ w2, const float* __restrict__ w3,
              bf16_t* __restrict__ o0, bf16_t* __restrict__ o1,
              bf16_t* __restrict__ o2, bf16_t* __restrict__ o3)
{
    // sizes: 110592, 36864, 147456, 147456  (cum: 110592, 147456, 294912, 442368)
    int i = blockIdx.x * 256 + threadIdx.x;
    if (i < 110592)       o0[i] = (bf16_t)w0[i];
    else if (i < 147456)  o1[i - 110592] = (bf16_t)w1[i - 110592];
    else if (i < 294912)  o2[i - 147456] = (bf16_t)w2[i - 147456];
    else if (i < 442368)  o3[i - 294912] = (bf16_t)w3[i - 294912];
}

extern "C" void kernel_launch(void* const* d_in, const int* in_sizes, int n_in,
                              void* d_out, int out_size, void* d_ws, size_t ws_size,
                              hipStream_t stream)
{
    (void)in_sizes; (void)n_in; (void)out_size; (void)ws_size;
    const float* x      = (const float*)d_in[0];
    const float* n1g    = (const float*)d_in[1];
    const float* n1b    = (const float*)d_in[2];
    const float* qkv_w  = (const float*)d_in[3];
    const float* qkv_b  = (const float*)d_in[4];
    const float* proj_w = (const float*)d_in[5];
    const float* proj_b = (const float*)d_in[6];
    const float* n2g    = (const float*)d_in[7];
    const float* n2b    = (const float*)d_in[8];
    const float* fc1_w  = (const float*)d_in[9];
    const float* fc1_b  = (const float*)d_in[10];
    const float* fc2_w  = (const float*)d_in[11];
    const float* fc2_b  = (const float*)d_in[12];
    float* out = (float*)d_out;

    char* ws = (char*)d_ws;
    size_t off = 0;
    auto alloc = [&](size_t nbytes) -> void* {
        off = (off + 255) & ~(size_t)255;
        void* p = ws + off;
        off += nbytes;
        return p;
    };

    bf16_t* Wq   = (bf16_t*)alloc((size_t)576 * 192 * 2);
    bf16_t* Wp   = (bf16_t*)alloc((size_t)192 * 192 * 2);
    bf16_t* W1   = (bf16_t*)alloc((size_t)768 * 192 * 2);
    bf16_t* W2   = (bf16_t*)alloc((size_t)192 * 768 * 2);
    bf16_t* Hbuf = (bf16_t*)alloc((size_t)110592 * 192 * 2);   // ln1 out -> O -> ln2 out
    bf16_t* Qkv  = (bf16_t*)alloc((size_t)110592 * 768 * 2);   // qkv(576)+Vt tail -> fc1(768)
    bf16_t* Vt   = Qkv + (size_t)110592 * 576;
    bf16_t* Sbuf = (bf16_t*)d_out;                              // 63.7 MB <= 85 MB, dead until proj

    cast_all<<<1728, 256, 0, stream>>>(qkv_w, proj_w, fc1_w, fc2_w, Wq, Wp, W1, W2);

    // LN1: x -> Hbuf (bf16)
    ln_fast<<<2048, 256, 0, stream>>>(x, n1g, n1b, Hbuf, 110592);
    // QKV: (110592x192)@(576x192)^T + b -> Qkv
    mgemm<128, 64, 1, 0><<<dim3(9, 864, 1), 256, 0, stream>>>(
        Hbuf, 192, 0, Wq, 192, 0, Qkv, 576, 0, qkv_b, 192, nullptr, nullptr);
    // Vt[h][e][m] = V[h][m][e]
    transpose_v<<<dim3(24, 36, 6), 256, 0, stream>>>(Qkv, Vt);
    // S = Q @ K^T per head (z=6): 2304x2304, K=1536   [grid 1944 % 8 == 0]
    mgemm<128, 128, 0, 1><<<dim3(18, 18, 6), 256, 0, stream>>>(
        Qkv, 27648, 1536, Qkv + 9216, 27648, 1536,
        Sbuf, 2304, (long)2304 * 2304, nullptr, 1536, nullptr, nullptr);
    // softmax rows (scale inside), in place
    softmax_fast<<<13824, 256, 0, stream>>>(Sbuf);
    // O = P @ Vt^T per head: 2304x1536, K=2304        [grid 1296 % 8 == 0]
    mgemm<128, 128, 0, 1><<<dim3(12, 18, 6), 256, 0, stream>>>(
        Sbuf, 2304, (long)2304 * 2304, Vt, 2304, (long)1536 * 2304,
        Hbuf, 9216, 1536, nullptr, 2304, nullptr, nullptr);
    // x1 = x + O @ Wp^T + pb -> out (fp32)
    mgemm<128, 64, 3, 0><<<dim3(3, 864, 1), 256, 0, stream>>>(
        Hbuf, 192, 0, Wp, 192, 0, nullptr, 192, 0, proj_b, 192, out, x);
    // LN2: x1 -> Hbuf (bf16)
    ln_fast<<<2048, 256, 0, stream>>>(out, n2g, n2b, Hbuf, 110592);
    // fc1 + gelu -> Qkv (768 cols)
    mgemm<128, 128, 2, 0><<<dim3(6, 864, 1), 256, 0, stream>>>(
        Hbuf, 192, 0, W1, 192, 0, Qkv, 768, 0, fc1_b, 192, nullptr, nullptr);
    // fc2 + resid -> out (fp32, in-place resid)
    mgemm<128, 64, 3, 0><<<dim3(3, 864, 1), 256, 0, stream>>>(
        Qkv, 768, 0, W2, 768, 0, nullptr, 192, 0, fc2_b, 768, out, out);
}

// Round 9
// 789.884 us; speedup vs baseline: 26.9434x; 1.0029x over previous
//
#include <hip/hip_runtime.h>

typedef __bf16 bf16_t;
typedef __attribute__((ext_vector_type(8))) __bf16 bf16x8;
typedef __attribute__((ext_vector_type(4))) float f32x4;

__device__ __forceinline__ float gelu_exact(float x) {
    return 0.5f * x * (1.0f + erff(x * 0.70710678118654752f));
}

#define AS1 __attribute__((address_space(1)))
#define AS3 __attribute__((address_space(3)))

// ================= 8-phase 256x256 MFMA GEMM (T2+T3+T4+T5), bf16 out =================
// C[m][n] = sum_k A[m][k]*B[n][k]. 512 thr = 8 waves (2M x 4N), per-wave 128x64.
// LDS (dynamic 128KB): [buf2][op2][kh2][256 rows][32 cols] bf16, 2-bit XOR swizzle
//   cw_lds = cw_logical ^ s2(row), s2(row) = (row ^ (row>>2)) & 3  (involution).
// Schedule per K-tile (4 phases): stage stream leads consumption by 3 half-tiles;
// stage order per tile [Bk0, Ak0, Bk1, Ak1]; each overwrite >=1 barrier after the
// region's last ds_read. vmcnt(6) once per K-tile (phase 4). setprio around MFMA.
#define MM_HALF(IH)                                                            \
    __builtin_amdgcn_s_setprio(1);                                             \
    _Pragma("unroll")                                                          \
    for (int u = 0; u < 4; ++u) {                                              \
        _Pragma("unroll")                                                      \
        for (int j = 0; j < 4; ++j)                                            \
            acc[(IH) * 4 + u][j] = __builtin_amdgcn_mfma_f32_16x16x32_bf16(    \
                a[u], b[j], acc[(IH) * 4 + u][j], 0, 0, 0);                    \
    }                                                                          \
    __builtin_amdgcn_s_setprio(0);

#define MIDBAR()                                                \
    asm volatile("" ::: "memory");                              \
    __builtin_amdgcn_s_barrier();                               \
    asm volatile("s_waitcnt lgkmcnt(0)" ::: "memory");

#define ENDBAR()                                                \
    asm volatile("" ::: "memory");                              \
    __builtin_amdgcn_s_barrier();                               \
    asm volatile("" ::: "memory");

__global__ __launch_bounds__(512, 2)
void gemm256(const bf16_t* __restrict__ A, int lda, long aBatch,
             const bf16_t* __restrict__ B, int ldb, long bBatch,
             bf16_t* __restrict__ C, int ldc, long cBatch, int K)
{
    extern __shared__ __align__(16) bf16_t lds[];
    const int t    = threadIdx.x;
    const int w    = t >> 6;
    const int lane = t & 63;
    const int wm   = w >> 2, wn = w & 3;     // 2 x 4 wave grid
    const int lrow = lane & 15;
    const int kq4  = lane >> 4;              // k-quarter within a 32-k half

    // bijective XCD swizzle (m204) — works for any grid size
    const unsigned gx = gridDim.x, gy = gridDim.y;
    unsigned nwg = gx * gy * gridDim.z;
    unsigned lin = (blockIdx.z * gy + blockIdx.y) * gx + blockIdx.x;
    {
        unsigned q = nwg >> 3, r = nwg & 7;
        unsigned xcd = lin & 7, idx = lin >> 3;
        lin = (xcd < r ? xcd * (q + 1) : r * (q + 1) + (xcd - r) * q) + idx;
    }
    const unsigned bx = lin % gx;
    const unsigned by = (lin / gx) % gy;
    const unsigned bz = lin / (gx * gy);

    const long n0 = (long)bx * 256;
    const long m0 = (long)by * 256;
    const bf16_t* Ap = A + (long)bz * aBatch + m0 * lda;
    const bf16_t* Bp = B + (long)bz * bBatch + n0 * ldb;
    C += (long)bz * cBatch;

    f32x4 acc[8][4] = {};

    // stage one K-half of one operand: 256 rows x 32 cols = 2 gloads/thread
    // LDS dest linear: buf*32768 + op*16384 + kh*8192 + e*4096 + t*8 (elems)
    // source column inverse-swizzled so LDS (row, cw) holds global (row, cw^s2(row))
    auto stage_half = [&](int buf, int op, int kh, int kt) {
        const bf16_t* base = op ? Bp : Ap;
        const int ld = op ? ldb : lda;
        #pragma unroll
        for (int e = 0; e < 2; ++e) {
            const int row = e * 128 + (t >> 2);
            const int cw  = (t & 3) ^ ((row ^ (row >> 2)) & 3);
            const bf16_t* src = base + (long)row * ld + (kt * 64 + kh * 32 + cw * 8);
            __builtin_amdgcn_global_load_lds(
                (AS1 void*)(bf16_t*)src,
                (AS3 void*)(lds + buf * 32768 + op * 16384 + kh * 8192 + e * 4096 + w * 512),
                16, 0, 0);
        }
    };

    bf16x8 a[4], b[4];
    auto rdA = [&](int c, int ks, int ih) {
        #pragma unroll
        for (int u = 0; u < 4; ++u) {
            const int row = wm * 128 + (ih * 4 + u) * 16 + lrow;
            const int cw  = kq4 ^ ((row ^ (row >> 2)) & 3);
            a[u] = *(const bf16x8*)(lds + c * 32768 + ks * 8192 + row * 32 + cw * 8);
        }
    };
    auto rdB = [&](int c, int ks) {
        #pragma unroll
        for (int u = 0; u < 4; ++u) {
            const int row = wn * 64 + u * 16 + lrow;
            const int cw  = kq4 ^ ((row ^ (row >> 2)) & 3);
            b[u] = *(const bf16x8*)(lds + c * 32768 + 16384 + ks * 8192 + row * 32 + cw * 8);
        }
    };

    const int nt = K >> 6;
    // prologue: tile0 fully, tile1 first 3 halves -> 3 halves (6 loads) in flight
    stage_half(0, 1, 0, 0); stage_half(0, 0, 0, 0);
    stage_half(0, 1, 1, 0); stage_half(0, 0, 1, 0);
    if (nt > 1) {
        stage_half(1, 1, 0, 1); stage_half(1, 0, 0, 1); stage_half(1, 1, 1, 1);
        asm volatile("s_waitcnt vmcnt(6)" ::: "memory");
    } else {
        asm volatile("s_waitcnt vmcnt(0)" ::: "memory");
    }
    __builtin_amdgcn_s_barrier();
    asm volatile("" ::: "memory");

    for (int kt = 0; kt < nt; ++kt) {
        const int c = kt & 1;
        // P1: ks0, rows-half 0 | stage (kt+1).Ak1 -> buf c^1 (safe: last read kt-1 P4)
        rdA(c, 0, 0); rdB(c, 0);
        if (kt + 1 < nt) stage_half(c ^ 1, 0, 1, kt + 1);
        MIDBAR(); MM_HALF(0); ENDBAR();
        // P2: ks0, rows-half 1 (B held in regs) | stage (kt+2).Bk0 -> buf c (B-p0 last read P1)
        rdA(c, 0, 1);
        if (kt + 2 < nt) stage_half(c, 1, 0, kt + 2);
        MIDBAR(); MM_HALF(1); ENDBAR();
        // P3: ks1, rows-half 0 | stage (kt+2).Ak0 -> buf c (A-p0 last read P2)
        rdA(c, 1, 0); rdB(c, 1);
        if (kt + 2 < nt) stage_half(c, 0, 0, kt + 2);
        MIDBAR(); MM_HALF(0); ENDBAR();
        // P4: ks1, rows-half 1 | stage (kt+2).Bk1 -> buf c (B-p1 last read P3)
        //     vmcnt: keep exactly 3 halves (6 loads) in flight -> tile kt+1 landed
        rdA(c, 1, 1);
        if (kt + 2 < nt) {
            stage_half(c, 1, 1, kt + 2);
            asm volatile("s_waitcnt vmcnt(6)" ::: "memory");
        } else {
            asm volatile("s_waitcnt vmcnt(0)" ::: "memory");
        }
        MIDBAR(); MM_HALF(1); ENDBAR();
    }

    // epilogue: D mapping col=lane&15, row=(lane>>4)*4+reg (m89/m91-verified)
    const int ccol  = lane & 15;
    const int crow4 = (lane >> 4) * 4;
    #pragma unroll
    for (int i = 0; i < 8; ++i) {
        long rowb = m0 + wm * 128 + i * 16 + crow4;
        #pragma unroll
        for (int j = 0; j < 4; ++j) {
            long col = n0 + wn * 64 + j * 16 + ccol;
            #pragma unroll
            for (int r = 0; r < 4; ++r)
                C[(rowb + r) * ldc + col] = (bf16_t)acc[i][j][r];
        }
    }
}

// ---------- MFMA bf16 GEMM: BK=64, T2 XOR swizzle, dbuf + counted-vmcnt ----------
// (verified rounds 5-7; used for qkv/proj/fc1/fc2 and as fallback for S/PV)
template<int BM, int BN, int EPI, int SWZ>
__global__ __launch_bounds__(256)
void mgemm(const bf16_t* __restrict__ A, int lda, long aBatch,
           const bf16_t* __restrict__ B, int ldb, long bBatch,
           bf16_t* __restrict__ C, int ldc, long cBatch,
           const float* __restrict__ bias, int K,
           float* __restrict__ Cf, const float* __restrict__ resid)
{
    constexpr int MR = BM / 32;
    constexpr int NR = BN / 32;
    constexpr int LPT = BM / 32 + BN / 32;
    __shared__ __align__(16) bf16_t As[2][BM * 64];
    __shared__ __align__(16) bf16_t Bs[2][BN * 64];
    const int t    = threadIdx.x;
    const int w    = t >> 6;
    const int lane = t & 63;
    const int wr   = w >> 1, wc = w & 1;

    unsigned bx = blockIdx.x, by = blockIdx.y, bz = blockIdx.z;
    if constexpr (SWZ) {
        const unsigned gx = gridDim.x, gy = gridDim.y, gz = gridDim.z;
        unsigned lin = (bz * gy + by) * gx + bx;
        const unsigned cpx = (gx * gy * gz) >> 3;
        lin = (lin & 7) * cpx + (lin >> 3);
        bx = lin % gx; lin /= gx;
        by = lin % gy; bz = lin / gy;
    }

    const long n0 = (long)bx * BN;
    const long m0 = (long)by * BM;
    A += (long)bz * aBatch;
    B += (long)bz * bBatch;
    if constexpr (EPI != 3) C += (long)bz * cBatch;

    f32x4 acc[MR][NR] = {};

    const int srow8  = t >> 3;
    const int schunk = (t & 7) ^ (srow8 & 7);
    const int lrow = lane & 15;
    const int kq4  = lane >> 4;

    auto stage = [&](int buf, int k0) {
        #pragma unroll
        for (int c = 0; c < BM / 32; ++c) {
            const bf16_t* src = A + (m0 + c * 32 + srow8) * (long)lda + (k0 + schunk * 8);
            __builtin_amdgcn_global_load_lds(
                (AS1 void*)(bf16_t*)src,
                (AS3 void*)(As[buf] + c * 2048 + w * 512), 16, 0, 0);
        }
        #pragma unroll
        for (int c = 0; c < BN / 32; ++c) {
            const bf16_t* src = B + (n0 + c * 32 + srow8) * (long)ldb + (k0 + schunk * 8);
            __builtin_amdgcn_global_load_lds(
                (AS1 void*)(bf16_t*)src,
                (AS3 void*)(Bs[buf] + c * 2048 + w * 512), 16, 0, 0);
        }
    };

    const int nt = K >> 6;
    stage(0, 0);
    int cur = 0;
    for (int kt = 0; kt < nt; ++kt) {
        if (kt + 1 < nt) {
            stage(cur ^ 1, (kt + 1) << 6);
            if constexpr (LPT == 8)
                asm volatile("s_waitcnt vmcnt(8)" ::: "memory");
            else
                asm volatile("s_waitcnt vmcnt(6)" ::: "memory");
        } else {
            asm volatile("s_waitcnt vmcnt(0)" ::: "memory");
        }
        __builtin_amdgcn_s_barrier();

        bf16x8 af[MR][2], bfr[NR][2];
        #pragma unroll
        for (int i = 0; i < MR; ++i) {
            const int row = wr * (BM / 2) + i * 16 + lrow;
            #pragma unroll
            for (int ks = 0; ks < 2; ++ks) {
                const int ch = (ks * 4 + kq4) ^ (row & 7);
                af[i][ks] = *(const bf16x8*)(As[cur] + row * 64 + ch * 8);
            }
        }
        #pragma unroll
        for (int j = 0; j < NR; ++j) {
            const int row = wc * (BN / 2) + j * 16 + lrow;
            #pragma unroll
            for (int ks = 0; ks < 2; ++ks) {
                const int ch = (ks * 4 + kq4) ^ (row & 7);
                bfr[j][ks] = *(const bf16x8*)(Bs[cur] + row * 64 + ch * 8);
            }
        }
        #pragma unroll
        for (int ks = 0; ks < 2; ++ks)
            #pragma unroll
            for (int i = 0; i < MR; ++i)
                #pragma unroll
                for (int j = 0; j < NR; ++j)
                    acc[i][j] = __builtin_amdgcn_mfma_f32_16x16x32_bf16(
                        af[i][ks], bfr[j][ks], acc[i][j], 0, 0, 0);

        asm volatile("s_waitcnt lgkmcnt(0)" ::: "memory");
        __builtin_amdgcn_s_barrier();
        cur ^= 1;
    }

    const int ccol  = lane & 15;
    const int crow4 = (lane >> 4) * 4;
    #pragma unroll
    for (int i = 0; i < MR; ++i) {
        long rowb = m0 + wr * (BM / 2) + i * 16 + crow4;
        #pragma unroll
        for (int j = 0; j < NR; ++j) {
            long col = n0 + wc * (BN / 2) + j * 16 + ccol;
            #pragma unroll
            for (int r = 0; r < 4; ++r) {
                float v = acc[i][j][r];
                long row = rowb + r;
                if constexpr (EPI == 0) {
                    C[row * ldc + col] = (bf16_t)v;
                } else if constexpr (EPI == 1) {
                    C[row * ldc + col] = (bf16_t)(v + bias[col]);
                } else if constexpr (EPI == 2) {
                    C[row * ldc + col] = (bf16_t)gelu_exact(v + bias[col]);
                } else {
                    long idx = row * ldc + col;
                    Cf[idx] = resid[idx] + v + bias[col];
                }
            }
        }
    }
}

// Vt[h][e][m] = V[h][m][e],  V[h][m][e] = Y[m*27648 + 18432 + h*1536 + e]
__global__ __launch_bounds__(256)
void transpose_v(const bf16_t* __restrict__ Y, bf16_t* __restrict__ Vt)
{
    __shared__ bf16_t tile[64][80];
    const int h  = blockIdx.z;
    const int e0 = blockIdx.x * 64;
    const int m0 = blockIdx.y * 64;
    const int t  = threadIdx.x;
    const int lr = t >> 3;
    const int lc8 = t & 7;

    #pragma unroll
    for (int i = 0; i < 64; i += 32) {
        int row = lr + i;
        bf16x8 vv = *(const bf16x8*)(Y + (long)(m0 + row) * 27648 + 18432 + h * 1536 + e0 + lc8 * 8);
        int cs = lc8 ^ (row >> 3);
        *(bf16x8*)&tile[row][cs * 8] = vv;
    }
    __syncthreads();
    #pragma unroll
    for (int i = 0; i < 64; i += 32) {
        int er = lr + i;
        bf16x8 vv;
        #pragma unroll
        for (int j = 0; j < 8; ++j) {
            int row = lc8 * 8 + j;
            int cs = (er >> 3) ^ lc8;
            vv[j] = tile[row][cs * 8 + (er & 7)];
        }
        *(bf16x8*)(Vt + ((long)h * 1536 + e0 + er) * 2304 + m0 + lc8 * 8) = vv;
    }
}

// LayerNorm: one WAVE per 192-row, shfl reductions, zero barriers. fp32 in -> bf16 out.
__global__ __launch_bounds__(256)
void ln_fast(const float* __restrict__ x, const float* __restrict__ g,
             const float* __restrict__ b, bf16_t* __restrict__ o, int nrows)
{
    const int lane = threadIdx.x & 63;
    const int wave = threadIdx.x >> 6;
    const float g0 = g[lane], g1 = g[lane + 64], g2 = g[lane + 128];
    const float b0 = b[lane], b1 = b[lane + 64], b2 = b[lane + 128];
    for (long row = (long)blockIdx.x * 4 + wave; row < nrows; row += (long)gridDim.x * 4) {
        const float* xr = x + row * 192;
        float v0 = xr[lane], v1 = xr[lane + 64], v2 = xr[lane + 128];
        float s  = v0 + v1 + v2;
        float ss = v0 * v0 + v1 * v1 + v2 * v2;
        #pragma unroll
        for (int d = 32; d > 0; d >>= 1) {
            s  += __shfl_xor(s, d);
            ss += __shfl_xor(ss, d);
        }
        float mean = s * (1.f / 192.f);
        float var  = ss * (1.f / 192.f) - mean * mean;
        float rs   = rsqrtf(var + 1e-5f);
        bf16_t* orow = o + row * 192;
        orow[lane]       = (bf16_t)((v0 - mean) * rs * g0 + b0);
        orow[lane + 64]  = (bf16_t)((v1 - mean) * rs * g1 + b1);
        orow[lane + 128] = (bf16_t)((v2 - mean) * rs * g2 + b2);
    }
}

// softmax over 2304 bf16 logits (scale folded), in place.
__global__ __launch_bounds__(256)
void softmax_fast(bf16_t* __restrict__ S)
{
    const float SC = 0.17677669529663687f;
    __shared__ float wmax[4], wsum[4];
    const long base = (long)blockIdx.x * 2304;
    const int t = threadIdx.x;
    const int lane = t & 63, w = t >> 6;
    float v[9];
    float mx = -1e30f;
    #pragma unroll
    for (int i = 0; i < 9; ++i) {
        v[i] = (float)S[base + t + i * 256] * SC;
        mx = fmaxf(mx, v[i]);
    }
    #pragma unroll
    for (int d = 32; d > 0; d >>= 1) mx = fmaxf(mx, __shfl_xor(mx, d));
    if (lane == 0) wmax[w] = mx;
    __syncthreads();
    mx = fmaxf(fmaxf(wmax[0], wmax[1]), fmaxf(wmax[2], wmax[3]));
    float sum = 0.f;
    #pragma unroll
    for (int i = 0; i < 9; ++i) { v[i] = __expf(v[i] - mx); sum += v[i]; }
    #pragma unroll
    for (int d = 32; d > 0; d >>= 1) sum += __shfl_xor(sum, d);
    if (lane == 0) wsum[w] = sum;
    __syncthreads();
    const float inv = 1.f / (wsum[0] + wsum[1] + wsum[2] + wsum[3]);
    #pragma unroll
    for (int i = 0; i < 9; ++i) S[base + t + i * 256] = (bf16_t)(v[i] * inv);
}

// all four weight casts in one launch
__global__ __launch_bounds__(256)
void cast_all(const float* __restrict__ w0, const float* __restrict__ w1,
              const float* __restrict__ w2, const float* __restrict__ w3,
              bf16_t* __restrict__ o0, bf16_t* __restrict__ o1,
              bf16_t* __restrict__ o2, bf16_t* __restrict__ o3)
{
    int i = blockIdx.x * 256 + threadIdx.x;
    if (i < 110592)       o0[i] = (bf16_t)w0[i];
    else if (i < 147456)  o1[i - 110592] = (bf16_t)w1[i - 110592];
    else if (i < 294912)  o2[i - 147456] = (bf16_t)w2[i - 147456];
    else if (i < 442368)  o3[i - 294912] = (bf16_t)w3[i - 294912];
}

extern "C" void kernel_launch(void* const* d_in, const int* in_sizes, int n_in,
                              void* d_out, int out_size, void* d_ws, size_t ws_size,
                              hipStream_t stream)
{
    (void)in_sizes; (void)n_in; (void)out_size; (void)ws_size;
    const float* x      = (const float*)d_in[0];
    const float* n1g    = (const float*)d_in[1];
    const float* n1b    = (const float*)d_in[2];
    const float* qkv_w  = (const float*)d_in[3];
    const float* qkv_b  = (const float*)d_in[4];
    const float* proj_w = (const float*)d_in[5];
    const float* proj_b = (const float*)d_in[6];
    const float* n2g    = (const float*)d_in[7];
    const float* n2b    = (const float*)d_in[8];
    const float* fc1_w  = (const float*)d_in[9];
    const float* fc1_b  = (const float*)d_in[10];
    const float* fc2_w  = (const float*)d_in[11];
    const float* fc2_b  = (const float*)d_in[12];
    float* out = (float*)d_out;

    char* ws = (char*)d_ws;
    size_t off = 0;
    auto alloc = [&](size_t nbytes) -> void* {
        off = (off + 255) & ~(size_t)255;
        void* p = ws + off;
        off += nbytes;
        return p;
    };

    bf16_t* Wq   = (bf16_t*)alloc((size_t)576 * 192 * 2);
    bf16_t* Wp   = (bf16_t*)alloc((size_t)192 * 192 * 2);
    bf16_t* W1   = (bf16_t*)alloc((size_t)768 * 192 * 2);
    bf16_t* W2   = (bf16_t*)alloc((size_t)192 * 768 * 2);
    bf16_t* Hbuf = (bf16_t*)alloc((size_t)110592 * 192 * 2);
    bf16_t* Qkv  = (bf16_t*)alloc((size_t)110592 * 768 * 2);
    bf16_t* Vt   = Qkv + (size_t)110592 * 576;
    bf16_t* Sbuf = (bf16_t*)d_out;

    // allow 128KB dynamic LDS for the 8-phase kernel (once per process)
    static bool attrOk = []() {
        return hipFuncSetAttribute(reinterpret_cast<const void*>(gemm256),
                                   hipFuncAttributeMaxDynamicSharedMemorySize,
                                   131072) == hipSuccess;
    }();

    cast_all<<<1728, 256, 0, stream>>>(qkv_w, proj_w, fc1_w, fc2_w, Wq, Wp, W1, W2);

    // LN1: x -> Hbuf (bf16)
    ln_fast<<<2048, 256, 0, stream>>>(x, n1g, n1b, Hbuf, 110592);
    // QKV: (110592x192)@(576x192)^T + b -> Qkv
    mgemm<128, 64, 1, 0><<<dim3(9, 864, 1), 256, 0, stream>>>(
        Hbuf, 192, 0, Wq, 192, 0, Qkv, 576, 0, qkv_b, 192, nullptr, nullptr);
    // Vt[h][e][m] = V[h][m][e]
    transpose_v<<<dim3(24, 36, 6), 256, 0, stream>>>(Qkv, Vt);
    // S = Q @ K^T per head: 2304x2304, K=1536
    if (attrOk) {
        gemm256<<<dim3(9, 9, 6), 512, 131072, stream>>>(
            Qkv, 27648, 1536, Qkv + 9216, 27648, 1536,
            Sbuf, 2304, (long)2304 * 2304, 1536);
    } else {
        mgemm<128, 128, 0, 1><<<dim3(18, 18, 6), 256, 0, stream>>>(
            Qkv, 27648, 1536, Qkv + 9216, 27648, 1536,
            Sbuf, 2304, (long)2304 * 2304, nullptr, 1536, nullptr, nullptr);
    }
    // softmax rows (scale inside), in place
    softmax_fast<<<13824, 256, 0, stream>>>(Sbuf);
    // O = P @ Vt^T per head: 2304x1536, K=2304
    if (attrOk) {
        gemm256<<<dim3(6, 9, 6), 512, 131072, stream>>>(
            Sbuf, 2304, (long)2304 * 2304, Vt, 2304, (long)1536 * 2304,
            Hbuf, 9216, 1536, 2304);
    } else {
        mgemm<128, 128, 0, 1><<<dim3(12, 18, 6), 256, 0, stream>>>(
            Sbuf, 2304, (long)2304 * 2304, Vt, 2304, (long)1536 * 2304,
            Hbuf, 9216, 1536, nullptr, 2304, nullptr, nullptr);
    }
    // x1 = x + O @ Wp^T + pb -> out (fp32)
    mgemm<128, 64, 3, 0><<<dim3(3, 864, 1), 256, 0, stream>>>(
        Hbuf, 192, 0, Wp, 192, 0, nullptr, 192, 0, proj_b, 192, out, x);
    // LN2: x1 -> Hbuf (bf16)
    ln_fast<<<2048, 256, 0, stream>>>(out, n2g, n2b, Hbuf, 110592);
    // fc1 + gelu -> Qkv (768 cols)
    mgemm<128, 128, 2, 0><<<dim3(6, 864, 1), 256, 0, stream>>>(
        Hbuf, 192, 0, W1, 192, 0, Qkv, 768, 0, fc1_b, 192, nullptr, nullptr);
    // fc2 + resid -> out (fp32, in-place resid)
    mgemm<128, 64, 3, 0><<<dim3(3, 864, 1), 256, 0, stream>>>(
        Qkv, 768, 0, W2, 768, 0, nullptr, 192, 0, fc2_b, 768, out, out);
}

// Round 11
// 773.478 us; speedup vs baseline: 27.5149x; 1.0212x over previous
//
#include <hip/hip_runtime.h>

typedef __bf16 bf16_t;
typedef __attribute__((ext_vector_type(8))) __bf16 bf16x8;
typedef __attribute__((ext_vector_type(4))) float f32x4;

__device__ __forceinline__ float gelu_exact(float x) {
    return 0.5f * x * (1.0f + erff(x * 0.70710678118654752f));
}

#define AS1 __attribute__((address_space(1)))
#define AS3 __attribute__((address_space(3)))

// ================= 8-phase 256x256 MFMA GEMM (T2+T3+T4+T5), bf16 out =================
// C[m][n] = sum_k A[m][k]*B[n][k]. 512 thr = 8 waves (2M x 4N), per-wave 128x64.
// LDS (dynamic 128KB): [buf2][op2][256 rows][64 cols] bf16 — 128B row stride +
// 3-bit XOR swizzle ch_lds = ch ^ (row&7): the round-5 measured-ZERO-conflict
// geometry (round-9's 64B-stride 2-bit variant measured 8.96e6 conflicts).
// Stage unit = row-quarter (64 rows x 64 cols = 1 gload/thread). 8 units/tile,
// all staged into buf c^1 during tile kt: P1:Bq01 P2:Bq23 P3:Aq0,2 P4:Aq1,3.
// Wait ledger: end-P1 vmcnt(2) (A-q1,q3 landed for P2), end-P4 vmcnt(2)
// (B+A-q0,q2 landed for next P1); never drains to 0 in steady state.
#define MM_HALF(IH)                                                            \
    __builtin_amdgcn_s_setprio(1);                                             \
    _Pragma("unroll")                                                          \
    for (int u = 0; u < 4; ++u) {                                              \
        _Pragma("unroll")                                                      \
        for (int j = 0; j < 4; ++j)                                            \
            acc[(IH) * 4 + u][j] = __builtin_amdgcn_mfma_f32_16x16x32_bf16(    \
                a[u], b[j], acc[(IH) * 4 + u][j], 0, 0, 0);                    \
    }                                                                          \
    __builtin_amdgcn_s_setprio(0);

#define MIDBAR()                                                \
    asm volatile("" ::: "memory");                              \
    __builtin_amdgcn_s_barrier();                               \
    asm volatile("s_waitcnt lgkmcnt(0)" ::: "memory");

#define ENDBAR()                                                \
    asm volatile("" ::: "memory");                              \
    __builtin_amdgcn_s_barrier();                               \
    asm volatile("" ::: "memory");

__global__ __launch_bounds__(512, 2)
void gemm256(const bf16_t* __restrict__ A, int lda, long aBatch,
             const bf16_t* __restrict__ B, int ldb, long bBatch,
             bf16_t* __restrict__ C, int ldc, long cBatch, int K)
{
    extern __shared__ __align__(16) bf16_t lds[];
    const int t    = threadIdx.x;
    const int lane = t & 63;
    const int w    = t >> 6;
    const int wm   = w >> 2, wn = w & 3;     // 2 x 4 wave grid
    const int lrow = lane & 15;
    const int kq4  = lane >> 4;              // k-quarter within a 32-k half

    // bijective XCD swizzle (m204)
    const unsigned gx = gridDim.x, gy = gridDim.y;
    unsigned nwg = gx * gy * gridDim.z;
    unsigned lin = (blockIdx.z * gy + blockIdx.y) * gx + blockIdx.x;
    {
        unsigned q = nwg >> 3, r = nwg & 7;
        unsigned xcd = lin & 7, idx = lin >> 3;
        lin = (xcd < r ? xcd * (q + 1) : r * (q + 1) + (xcd - r) * q) + idx;
    }
    const unsigned bx = lin % gx;
    const unsigned by = (lin / gx) % gy;
    const unsigned bz = lin / (gx * gy);

    const long n0 = (long)bx * 256;
    const long m0 = (long)by * 256;
    const bf16_t* Ap = A + (long)bz * aBatch + m0 * lda;
    const bf16_t* Bp = B + (long)bz * bBatch + n0 * ldb;
    C += (long)bz * cBatch;

    f32x4 acc[8][4] = {};

    // stage one row-quarter of one operand: 64 rows x 64 cols = 1 gload/thread.
    // LDS linear: buf*32768 + op*16384 + q*4096 + t*8 (elems); thread t covers
    // row q*64+(t>>3), chunk t&7. Source chunk inverse-swizzled: ch^(row&7).
    auto stage_q = [&](int buf, int op, int q, int kt) {
        const bf16_t* base = op ? Bp : Ap;
        const int ld = op ? ldb : lda;
        const int row = q * 64 + (t >> 3);
        const int ch  = (t & 7) ^ (row & 7);
        const bf16_t* src = base + (long)row * ld + (kt * 64 + ch * 8);
        __builtin_amdgcn_global_load_lds(
            (AS1 void*)(bf16_t*)src,
            (AS3 void*)(lds + buf * 32768 + op * 16384 + q * 4096 + t * 8),
            16, 0, 0);
    };

    bf16x8 a[4], b[4];
    auto rdA = [&](int c, int ks, int ih) {
        #pragma unroll
        for (int u = 0; u < 4; ++u) {
            const int row = wm * 128 + (ih * 4 + u) * 16 + lrow;
            const int ch  = (ks * 4 + kq4) ^ (row & 7);
            a[u] = *(const bf16x8*)(lds + c * 32768 + row * 64 + ch * 8);
        }
    };
    auto rdB = [&](int c, int ks) {
        #pragma unroll
        for (int u = 0; u < 4; ++u) {
            const int row = wn * 64 + u * 16 + lrow;
            const int ch  = (ks * 4 + kq4) ^ (row & 7);
            b[u] = *(const bf16x8*)(lds + c * 32768 + 16384 + row * 64 + ch * 8);
        }
    };

    const int nt = K >> 6;      // all call sites K % 64 == 0, nt >= 2
    // prologue: tile0 fully staged; A-q1,q3 may stay in flight past the barrier
    stage_q(0, 1, 0, 0); stage_q(0, 1, 1, 0); stage_q(0, 1, 2, 0); stage_q(0, 1, 3, 0);
    stage_q(0, 0, 0, 0); stage_q(0, 0, 2, 0);
    stage_q(0, 0, 1, 0); stage_q(0, 0, 3, 0);
    asm volatile("s_waitcnt vmcnt(2)" ::: "memory");
    __builtin_amdgcn_s_barrier();
    asm volatile("" ::: "memory");

    for (int kt = 0; kt < nt; ++kt) {
        const int c = kt & 1;
        const bool pf = (kt + 1 < nt);
        // P1: ks0 rows-half0 (A-q0,q2 + B all, landed) | stage kt+1 B-q0,q1
        rdA(c, 0, 0); rdB(c, 0);
        if (pf) { stage_q(c ^ 1, 1, 0, kt + 1); stage_q(c ^ 1, 1, 1, kt + 1); }
        MIDBAR(); MM_HALF(0);
        if (pf) asm volatile("s_waitcnt vmcnt(2)" ::: "memory");   // A-q1,q3 of tile kt landed
        else    asm volatile("s_waitcnt vmcnt(0)" ::: "memory");
        ENDBAR();
        // P2: ks0 rows-half1 (A-q1,q3; B held in regs) | stage kt+1 B-q2,q3
        rdA(c, 0, 1);
        if (pf) { stage_q(c ^ 1, 1, 2, kt + 1); stage_q(c ^ 1, 1, 3, kt + 1); }
        MIDBAR(); MM_HALF(1); ENDBAR();
        // P3: ks1 rows-half0 (same units, ks1 cols — landed) | stage kt+1 A-q0,q2
        rdA(c, 1, 0); rdB(c, 1);
        if (pf) { stage_q(c ^ 1, 0, 0, kt + 1); stage_q(c ^ 1, 0, 2, kt + 1); }
        MIDBAR(); MM_HALF(0); ENDBAR();
        // P4: ks1 rows-half1 | stage kt+1 A-q1,q3; retire B+A-q0,q2 of kt+1
        rdA(c, 1, 1);
        if (pf) { stage_q(c ^ 1, 0, 1, kt + 1); stage_q(c ^ 1, 0, 3, kt + 1); }
        MIDBAR(); MM_HALF(1);
        if (pf) asm volatile("s_waitcnt vmcnt(2)" ::: "memory");   // kt+1 B+A-q0,q2 landed
        else    asm volatile("s_waitcnt vmcnt(0)" ::: "memory");
        ENDBAR();
    }

    // epilogue: D mapping col=lane&15, row=(lane>>4)*4+reg (m89/m91-verified)
    const int ccol  = lane & 15;
    const int crow4 = (lane >> 4) * 4;
    #pragma unroll
    for (int i = 0; i < 8; ++i) {
        long rowb = m0 + wm * 128 + i * 16 + crow4;
        #pragma unroll
        for (int j = 0; j < 4; ++j) {
            long col = n0 + wn * 64 + j * 16 + ccol;
            #pragma unroll
            for (int r = 0; r < 4; ++r)
                C[(rowb + r) * ldc + col] = (bf16_t)acc[i][j][r];
        }
    }
}

// ---------- MFMA bf16 GEMM: BK=64, T2 XOR swizzle, dbuf + counted-vmcnt ----------
// (verified rounds 5-7; used for qkv/proj/fc1/fc2 and as fallback for S/PV)
template<int BM, int BN, int EPI, int SWZ>
__global__ __launch_bounds__(256)
void mgemm(const bf16_t* __restrict__ A, int lda, long aBatch,
           const bf16_t* __restrict__ B, int ldb, long bBatch,
           bf16_t* __restrict__ C, int ldc, long cBatch,
           const float* __restrict__ bias, int K,
           float* __restrict__ Cf, const float* __restrict__ resid)
{
    constexpr int MR = BM / 32;
    constexpr int NR = BN / 32;
    constexpr int LPT = BM / 32 + BN / 32;
    __shared__ __align__(16) bf16_t As[2][BM * 64];
    __shared__ __align__(16) bf16_t Bs[2][BN * 64];
    const int t    = threadIdx.x;
    const int w    = t >> 6;
    const int lane = t & 63;
    const int wr   = w >> 1, wc = w & 1;

    unsigned bx = blockIdx.x, by = blockIdx.y, bz = blockIdx.z;
    if constexpr (SWZ) {
        const unsigned gx = gridDim.x, gy = gridDim.y, gz = gridDim.z;
        unsigned lin = (bz * gy + by) * gx + bx;
        const unsigned cpx = (gx * gy * gz) >> 3;
        lin = (lin & 7) * cpx + (lin >> 3);
        bx = lin % gx; lin /= gx;
        by = lin % gy; bz = lin / gy;
    }

    const long n0 = (long)bx * BN;
    const long m0 = (long)by * BM;
    A += (long)bz * aBatch;
    B += (long)bz * bBatch;
    if constexpr (EPI != 3) C += (long)bz * cBatch;

    f32x4 acc[MR][NR] = {};

    const int srow8  = t >> 3;
    const int schunk = (t & 7) ^ (srow8 & 7);
    const int lrow = lane & 15;
    const int kq4  = lane >> 4;

    auto stage = [&](int buf, int k0) {
        #pragma unroll
        for (int c = 0; c < BM / 32; ++c) {
            const bf16_t* src = A + (m0 + c * 32 + srow8) * (long)lda + (k0 + schunk * 8);
            __builtin_amdgcn_global_load_lds(
                (AS1 void*)(bf16_t*)src,
                (AS3 void*)(As[buf] + c * 2048 + w * 512), 16, 0, 0);
        }
        #pragma unroll
        for (int c = 0; c < BN / 32; ++c) {
            const bf16_t* src = B + (n0 + c * 32 + srow8) * (long)ldb + (k0 + schunk * 8);
            __builtin_amdgcn_global_load_lds(
                (AS1 void*)(bf16_t*)src,
                (AS3 void*)(Bs[buf] + c * 2048 + w * 512), 16, 0, 0);
        }
    };

    const int nt = K >> 6;
    stage(0, 0);
    int cur = 0;
    for (int kt = 0; kt < nt; ++kt) {
        if (kt + 1 < nt) {
            stage(cur ^ 1, (kt + 1) << 6);
            if constexpr (LPT == 8)
                asm volatile("s_waitcnt vmcnt(8)" ::: "memory");
            else
                asm volatile("s_waitcnt vmcnt(6)" ::: "memory");
        } else {
            asm volatile("s_waitcnt vmcnt(0)" ::: "memory");
        }
        __builtin_amdgcn_s_barrier();

        bf16x8 af[MR][2], bfr[NR][2];
        #pragma unroll
        for (int i = 0; i < MR; ++i) {
            const int row = wr * (BM / 2) + i * 16 + lrow;
            #pragma unroll
            for (int ks = 0; ks < 2; ++ks) {
                const int ch = (ks * 4 + kq4) ^ (row & 7);
                af[i][ks] = *(const bf16x8*)(As[cur] + row * 64 + ch * 8);
            }
        }
        #pragma unroll
        for (int j = 0; j < NR; ++j) {
            const int row = wc * (BN / 2) + j * 16 + lrow;
            #pragma unroll
            for (int ks = 0; ks < 2; ++ks) {
                const int ch = (ks * 4 + kq4) ^ (row & 7);
                bfr[j][ks] = *(const bf16x8*)(Bs[cur] + row * 64 + ch * 8);
            }
        }
        #pragma unroll
        for (int ks = 0; ks < 2; ++ks)
            #pragma unroll
            for (int i = 0; i < MR; ++i)
                #pragma unroll
                for (int j = 0; j < NR; ++j)
                    acc[i][j] = __builtin_amdgcn_mfma_f32_16x16x32_bf16(
                        af[i][ks], bfr[j][ks], acc[i][j], 0, 0, 0);

        asm volatile("s_waitcnt lgkmcnt(0)" ::: "memory");
        __builtin_amdgcn_s_barrier();
        cur ^= 1;
    }

    const int ccol  = lane & 15;
    const int crow4 = (lane >> 4) * 4;
    #pragma unroll
    for (int i = 0; i < MR; ++i) {
        long rowb = m0 + wr * (BM / 2) + i * 16 + crow4;
        #pragma unroll
        for (int j = 0; j < NR; ++j) {
            long col = n0 + wc * (BN / 2) + j * 16 + ccol;
            #pragma unroll
            for (int r = 0; r < 4; ++r) {
                float v = acc[i][j][r];
                long row = rowb + r;
                if constexpr (EPI == 0) {
                    C[row * ldc + col] = (bf16_t)v;
                } else if constexpr (EPI == 1) {
                    C[row * ldc + col] = (bf16_t)(v + bias[col]);
                } else if constexpr (EPI == 2) {
                    C[row * ldc + col] = (bf16_t)gelu_exact(v + bias[col]);
                } else {
                    long idx = row * ldc + col;
                    Cf[idx] = resid[idx] + v + bias[col];
                }
            }
        }
    }
}

// Vt[h][e][m] = V[h][m][e],  V[h][m][e] = Y[m*27648 + 18432 + h*1536 + e]
__global__ __launch_bounds__(256)
void transpose_v(const bf16_t* __restrict__ Y, bf16_t* __restrict__ Vt)
{
    __shared__ bf16_t tile[64][80];
    const int h  = blockIdx.z;
    const int e0 = blockIdx.x * 64;
    const int m0 = blockIdx.y * 64;
    const int t  = threadIdx.x;
    const int lr = t >> 3;
    const int lc8 = t & 7;

    #pragma unroll
    for (int i = 0; i < 64; i += 32) {
        int row = lr + i;
        bf16x8 vv = *(const bf16x8*)(Y + (long)(m0 + row) * 27648 + 18432 + h * 1536 + e0 + lc8 * 8);
        int cs = lc8 ^ (row >> 3);
        *(bf16x8*)&tile[row][cs * 8] = vv;
    }
    __syncthreads();
    #pragma unroll
    for (int i = 0; i < 64; i += 32) {
        int er = lr + i;
        bf16x8 vv;
        #pragma unroll
        for (int j = 0; j < 8; ++j) {
            int row = lc8 * 8 + j;
            int cs = (er >> 3) ^ lc8;
            vv[j] = tile[row][cs * 8 + (er & 7)];
        }
        *(bf16x8*)(Vt + ((long)h * 1536 + e0 + er) * 2304 + m0 + lc8 * 8) = vv;
    }
}

// LayerNorm: one WAVE per 192-row, shfl reductions, zero barriers. fp32 in -> bf16 out.
__global__ __launch_bounds__(256)
void ln_fast(const float* __restrict__ x, const float* __restrict__ g,
             const float* __restrict__ b, bf16_t* __restrict__ o, int nrows)
{
    const int lane = threadIdx.x & 63;
    const int wave = threadIdx.x >> 6;
    const float g0 = g[lane], g1 = g[lane + 64], g2 = g[lane + 128];
    const float b0 = b[lane], b1 = b[lane + 64], b2 = b[lane + 128];
    for (long row = (long)blockIdx.x * 4 + wave; row < nrows; row += (long)gridDim.x * 4) {
        const float* xr = x + row * 192;
        float v0 = xr[lane], v1 = xr[lane + 64], v2 = xr[lane + 128];
        float s  = v0 + v1 + v2;
        float ss = v0 * v0 + v1 * v1 + v2 * v2;
        #pragma unroll
        for (int d = 32; d > 0; d >>= 1) {
            s  += __shfl_xor(s, d);
            ss += __shfl_xor(ss, d);
        }
        float mean = s * (1.f / 192.f);
        float var  = ss * (1.f / 192.f) - mean * mean;
        float rs   = rsqrtf(var + 1e-5f);
        bf16_t* orow = o + row * 192;
        orow[lane]       = (bf16_t)((v0 - mean) * rs * g0 + b0);
        orow[lane + 64]  = (bf16_t)((v1 - mean) * rs * g1 + b1);
        orow[lane + 128] = (bf16_t)((v2 - mean) * rs * g2 + b2);
    }
}

// softmax over 2304 bf16 logits (scale folded), in place.
__global__ __launch_bounds__(256)
void softmax_fast(bf16_t* __restrict__ S)
{
    const float SC = 0.17677669529663687f;
    __shared__ float wmax[4], wsum[4];
    const long base = (long)blockIdx.x * 2304;
    const int t = threadIdx.x;
    const int lane = t & 63, w = t >> 6;
    float v[9];
    float mx = -1e30f;
    #pragma unroll
    for (int i = 0; i < 9; ++i) {
        v[i] = (float)S[base + t + i * 256] * SC;
        mx = fmaxf(mx, v[i]);
    }
    #pragma unroll
    for (int d = 32; d > 0; d >>= 1) mx = fmaxf(mx, __shfl_xor(mx, d));
    if (lane == 0) wmax[w] = mx;
    __syncthreads();
    mx = fmaxf(fmaxf(wmax[0], wmax[1]), fmaxf(wmax[2], wmax[3]));
    float sum = 0.f;
    #pragma unroll
    for (int i = 0; i < 9; ++i) { v[i] = __expf(v[i] - mx); sum += v[i]; }
    #pragma unroll
    for (int d = 32; d > 0; d >>= 1) sum += __shfl_xor(sum, d);
    if (lane == 0) wsum[w] = sum;
    __syncthreads();
    const float inv = 1.f / (wsum[0] + wsum[1] + wsum[2] + wsum[3]);
    #pragma unroll
    for (int i = 0; i < 9; ++i) S[base + t + i * 256] = (bf16_t)(v[i] * inv);
}

// all four weight casts in one launch
__global__ __launch_bounds__(256)
void cast_all(const float* __restrict__ w0, const float* __restrict__ w1,
              const float* __restrict__ w2, const float* __restrict__ w3,
              bf16_t* __restrict__ o0, bf16_t* __restrict__ o1,
              bf16_t* __restrict__ o2, bf16_t* __restrict__ o3)
{
    int i = blockIdx.x * 256 + threadIdx.x;
    if (i < 110592)       o0[i] = (bf16_t)w0[i];
    else if (i < 147456)  o1[i - 110592] = (bf16_t)w1[i - 110592];
    else if (i < 294912)  o2[i - 147456] = (bf16_t)w2[i - 147456];
    else if (i < 442368)  o3[i - 294912] = (bf16_t)w3[i - 294912];
}

extern "C" void kernel_launch(void* const* d_in, const int* in_sizes, int n_in,
                              void* d_out, int out_size, void* d_ws, size_t ws_size,
                              hipStream_t stream)
{
    (void)in_sizes; (void)n_in; (void)out_size; (void)ws_size;
    const float* x      = (const float*)d_in[0];
    const float* n1g    = (const float*)d_in[1];
    const float* n1b    = (const float*)d_in[2];
    const float* qkv_w  = (const float*)d_in[3];
    const float* qkv_b  = (const float*)d_in[4];
    const float* proj_w = (const float*)d_in[5];
    const float* proj_b = (const float*)d_in[6];
    const float* n2g    = (const float*)d_in[7];
    const float* n2b    = (const float*)d_in[8];
    const float* fc1_w  = (const float*)d_in[9];
    const float* fc1_b  = (const float*)d_in[10];
    const float* fc2_w  = (const float*)d_in[11];
    const float* fc2_b  = (const float*)d_in[12];
    float* out = (float*)d_out;

    char* ws = (char*)d_ws;
    size_t off = 0;
    auto alloc = [&](size_t nbytes) -> void* {
        off = (off + 255) & ~(size_t)255;
        void* p = ws + off;
        off += nbytes;
        return p;
    };

    bf16_t* Wq   = (bf16_t*)alloc((size_t)576 * 192 * 2);
    bf16_t* Wp   = (bf16_t*)alloc((size_t)192 * 192 * 2);
    bf16_t* W1   = (bf16_t*)alloc((size_t)768 * 192 * 2);
    bf16_t* W2   = (bf16_t*)alloc((size_t)192 * 768 * 2);
    bf16_t* Hbuf = (bf16_t*)alloc((size_t)110592 * 192 * 2);
    bf16_t* Qkv  = (bf16_t*)alloc((size_t)110592 * 768 * 2);
    bf16_t* Vt   = Qkv + (size_t)110592 * 576;
    bf16_t* Sbuf = (bf16_t*)d_out;

    // allow 128KB dynamic LDS for the 8-phase kernel (once per process)
    static bool attrOk = []() {
        return hipFuncSetAttribute(reinterpret_cast<const void*>(gemm256),
                                   hipFuncAttributeMaxDynamicSharedMemorySize,
                                   131072) == hipSuccess;
    }();

    cast_all<<<1728, 256, 0, stream>>>(qkv_w, proj_w, fc1_w, fc2_w, Wq, Wp, W1, W2);

    // LN1: x -> Hbuf (bf16)
    ln_fast<<<2048, 256, 0, stream>>>(x, n1g, n1b, Hbuf, 110592);
    // QKV: (110592x192)@(576x192)^T + b -> Qkv
    mgemm<128, 64, 1, 0><<<dim3(9, 864, 1), 256, 0, stream>>>(
        Hbuf, 192, 0, Wq, 192, 0, Qkv, 576, 0, qkv_b, 192, nullptr, nullptr);
    // Vt[h][e][m] = V[h][m][e]
    transpose_v<<<dim3(24, 36, 6), 256, 0, stream>>>(Qkv, Vt);
    // S = Q @ K^T per head: 2304x2304, K=1536
    if (attrOk) {
        gemm256<<<dim3(9, 9, 6), 512, 131072, stream>>>(
            Qkv, 27648, 1536, Qkv + 9216, 27648, 1536,
            Sbuf, 2304, (long)2304 * 2304, 1536);
    } else {
        mgemm<128, 128, 0, 1><<<dim3(18, 18, 6), 256, 0, stream>>>(
            Qkv, 27648, 1536, Qkv + 9216, 27648, 1536,
            Sbuf, 2304, (long)2304 * 2304, nullptr, 1536, nullptr, nullptr);
    }
    // softmax rows (scale inside), in place
    softmax_fast<<<13824, 256, 0, stream>>>(Sbuf);
    // O = P @ Vt^T per head: 2304x1536, K=2304
    if (attrOk) {
        gemm256<<<dim3(6, 9, 6), 512, 131072, stream>>>(
            Sbuf, 2304, (long)2304 * 2304, Vt, 2304, (long)1536 * 2304,
            Hbuf, 9216, 1536, 2304);
    } else {
        mgemm<128, 128, 0, 1><<<dim3(12, 18, 6), 256, 0, stream>>>(
            Sbuf, 2304, (long)2304 * 2304, Vt, 2304, (long)1536 * 2304,
            Hbuf, 9216, 1536, nullptr, 2304, nullptr, nullptr);
    }
    // x1 = x + O @ Wp^T + pb -> out (fp32)
    mgemm<128, 64, 3, 0><<<dim3(3, 864, 1), 256, 0, stream>>>(
        Hbuf, 192, 0, Wp, 192, 0, nullptr, 192, 0, proj_b, 192, out, x);
    // LN2: x1 -> Hbuf (bf16)
    ln_fast<<<2048, 256, 0, stream>>>(out, n2g, n2b, Hbuf, 110592);
    // fc1 + gelu -> Qkv (768 cols)
    mgemm<128, 128, 2, 0><<<dim3(6, 864, 1), 256, 0, stream>>>(
        Hbuf, 192, 0, W1, 192, 0, Qkv, 768, 0, fc1_b, 192, nullptr, nullptr);
    // fc2 + resid -> out (fp32, in-place resid)
    mgemm<128, 64, 3, 0><<<dim3(3, 864, 1), 256, 0, stream>>>(
        Qkv, 768, 0, W2, 768, 0, nullptr, 192, 0, fc2_b, 768, out, out);
}